// Round 8
// baseline (274.888 us; speedup 1.0000x reference)
//
#include <hip/hip_runtime.h>

#define DI __device__ __forceinline__

typedef unsigned short u16;
typedef __attribute__((__ext_vector_type__(8))) __bf16 bf16x8;
typedef __attribute__((__ext_vector_type__(4))) float f32x4;
typedef __attribute__((__ext_vector_type__(4))) unsigned short u16x4;
typedef __attribute__((__ext_vector_type__(8))) unsigned short u16x8;

DI float bf2f(u16 u) { union { unsigned int i; float f; } x; x.i = ((unsigned int)u) << 16; return x.f; }
DI u16 f2bf(float f) {
  union { float f; unsigned int i; } x; x.f = f;
  unsigned int r = x.i + 0x7fffu + ((x.i >> 16) & 1u);
  return (u16)(r >> 16);
}

// async global->LDS, 16B per lane; LDS dest = wave-uniform base + lane*16
DI void gload_lds16(const void* g, void* lds) {
  __builtin_amdgcn_global_load_lds((const __attribute__((address_space(1))) unsigned int*)g,
                                   (__attribute__((address_space(3))) unsigned int*)lds, 16, 0, 0);
}

#define MFMA16(a, b, c) __builtin_amdgcn_mfma_f32_16x16x32_bf16((a), (b), (c), 0, 0, 0)

// =====================================================================================
// gemm8q: C[M,N] = A[M,K] @ Bt[N,K]^T * scale + bias   (m201-style 8-phase, split tiles)
// BM=BN=256, BK=64 per K-tile, 2 K-tiles per loop iteration (even buf0, odd buf1).
// 8 waves (2M x 4N) with SPLIT wave tiles:
//   wave rows: {wm*64..wm*64+63} u {128+wm*64..+63}  (mf 0-3 lo / 4-7 hi)
//   wave cols: {wn*32..wn*32+31} u {128+wn*32..+31}  (nf 0-1 lo / 2-3 hi)
// -> half-tile deadlines stagger: Ah0,Bh0 @P1; Bh1 @P2; Ah1 @P3 of each K-tile.
// Per phase: {ds_read quadrant frags (0/4/8/12 b128), stage 1 half-tile (2 gload_lds),
//   barrier, lgkmcnt(0), sched_barrier, setprio(1), 16 MFMA, setprio(0), barrier}.
// Gray quadrant order (Alo,Blo)->(Alo,Bhi)->(Ahi,Bhi)->(Ahi,Blo); bLo held in regs.
// vmcnt(6) ONLY at phases 4 and 8 (3 half-tiles in flight); vmcnt(0) there in the
// final iteration (guards off). Stage targets verified free (last reader >=1 barrier
// earlier); k-granule XOR LDS layout (conflict-free ds_read_b128; linear gload_lds
// dest, pre-permuted GLOBAL source -- rule 21).
// LDS per buffer (u16): Ah0 @0, Ah1 @8192, Bh0 @16384, Bh1 @24576; 2 bufs = 128KB.
// Requires M%256==0, N%256==0, K%128==0 (NKT even >=2). grid (N/256,M/256,z); (gx*gy)%8==0.
// =====================================================================================
template<bool RELU, bool OUT_BF16, bool HAS_BIAS>
__global__ __launch_bounds__(512, 2)
void gemm8q(const u16* __restrict__ A, long long sAb, int lda,
            const u16* __restrict__ Bt, long long sBb, int ldb,
            const float* __restrict__ bias,
            void* __restrict__ C, long long sCb, int ldc,
            int K, float scale)
{
  extern __shared__ __align__(16) u16 lds[];

  const int tid = threadIdx.x;
  const int w = tid >> 6, l = tid & 63;
  const int wm = w >> 2, wn = w & 3;

  // XCD swizzle on flattened (x,y) per z-slice
  const int gx = gridDim.x;
  const int nwg = gx * gridDim.y;
  const int f = blockIdx.x + gx * blockIdx.y;
  const int fs = (f & 7) * (nwg >> 3) + (f >> 3);
  const int bx = fs % gx, by = fs / gx;

  const long long bm = (long long)by * 256;
  const long long bn = (long long)bx * 256;
  const u16* Ab = A + (long long)blockIdx.z * sAb;
  const u16* Btb = Bt + (long long)blockIdx.z * sBb;

  // staging source (per-lane, pre-permuted k-granule). One issue = 64 rows x 64 k.
  const int trow = tid >> 3;
  const int tg = (tid & 7) ^ (trow & 7);
  const u16* gA = Ab + (bm + trow) * (long long)lda + tg * 8;
  const u16* gB = Btb + (bn + trow) * (long long)ldb + tg * 8;

  // stage one half-tile (128 rows = 2 issues). dOff = buf*32768 + region + h*8192
#define STG(gP, ld, h, t, dOff) { \
    const u16* s_ = (gP) + (long long)((h) * 128) * (ld) + (long long)(t) * 64; \
    u16* d_ = lds + (dOff) + w * 512; \
    gload_lds16(s_, d_); \
    gload_lds16(s_ + (long long)64 * (ld), d_ + 4096); }
#define STAGE_A(t, h, buf) STG(gA, lda, h, t, (buf) * 32768 + (h) * 8192)
#define STAGE_B(t, h, buf) STG(gB, ldb, h, t, (buf) * 32768 + 16384 + (h) * 8192)

  // fragment read bases (u16 units); granule g of row r stored at slot g^(r&7)
  const int slotX = ((l >> 4) ^ (l & 7)) * 8;
  const int aRowB = (wm * 64 + (l & 15)) * 64 + slotX;      // + region offset
  const int bRowB = (wn * 32 + (l & 15)) * 64 + slotX;
  const int aLoOff = aRowB;            // Ah0 region @0
  const int aHiOff = 8192 + aRowB;     // Ah1
  const int bLoOff = 16384 + bRowB;    // Bh0
  const int bHiOff = 24576 + bRowB;    // Bh1

#define RD_A(base) { _Pragma("unroll") for (int mf = 0; mf < 4; ++mf) { \
    aF[mf][0] = *(const bf16x8*)(lds + ((base) + mf * 1024)); \
    aF[mf][1] = *(const bf16x8*)(lds + (((base) + mf * 1024) ^ 32)); } }
#define RD_B(dst, base) { _Pragma("unroll") for (int nf = 0; nf < 2; ++nf) { \
    dst[nf][0] = *(const bf16x8*)(lds + ((base) + nf * 1024)); \
    dst[nf][1] = *(const bf16x8*)(lds + (((base) + nf * 1024) ^ 32)); } }
#define QUAD(MO, NO, B) { _Pragma("unroll") for (int mf = 0; mf < 4; ++mf) { \
    _Pragma("unroll") for (int nf = 0; nf < 2; ++nf) { \
      acc[mf + MO][nf + NO] = MFMA16(aF[mf][0], B[nf][0], acc[mf + MO][nf + NO]); \
      acc[mf + MO][nf + NO] = MFMA16(aF[mf][1], B[nf][1], acc[mf + MO][nf + NO]); } } }
#define PH_MID() \
    __builtin_amdgcn_s_barrier(); \
    asm volatile("s_waitcnt lgkmcnt(0)" ::: "memory"); \
    __builtin_amdgcn_sched_barrier(0); \
    __builtin_amdgcn_s_setprio(1);
#define PH_END() \
    __builtin_amdgcn_s_setprio(0); \
    __builtin_amdgcn_s_barrier();

  f32x4 acc[8][4] = {};
  bf16x8 aF[4][2], bLo[2][2], bHi[2][2];
  const int NKT = K >> 6;
  const int NIT = NKT >> 1;

  // ---- prologue: tile0 full (8 loads), tile1 minus Ah1 (6 loads) ----
  STAGE_A(0, 0, 0); STAGE_A(0, 1, 0); STAGE_B(0, 0, 0); STAGE_B(0, 1, 0);
  STAGE_A(1, 0, 1); STAGE_B(1, 0, 1); STAGE_B(1, 1, 1);
  asm volatile("s_waitcnt vmcnt(6)" ::: "memory");
  __builtin_amdgcn_s_barrier();

  for (int i = 0; i < NIT; ++i) {
    const bool go = (i + 1) < NIT;
    const int btile = 2 * i + 1, c = 2 * i + 2, d = 2 * i + 3;

    // ======== tile a = 2i (buf0) ========
    // P1 (Alo,Blo)
    RD_A(aLoOff); RD_B(bLo, bLoOff);
    STAGE_A(btile, 1, 1);                         // Ah1(b) -> buf1 (freed @p7 of i-1)
    PH_MID(); QUAD(0, 0, bLo); PH_END();
    // P2 (Alo,Bhi)
    RD_B(bHi, bHiOff);
    if (go) STAGE_A(c, 0, 0);                     // buf0.Ah0 freed @P1
    PH_MID(); QUAD(0, 2, bHi); PH_END();
    // P3 (Ahi,Bhi)
    RD_A(aHiOff);
    if (go) STAGE_B(c, 0, 0);                     // buf0.Bh0 freed @P1 (bLo held in regs)
    PH_MID(); QUAD(4, 2, bHi); PH_END();
    // P4 (Ahi,Blo) -- no reads; counted wait
    if (go) STAGE_B(c, 1, 0);                     // buf0.Bh1 freed @P2
    if (go) asm volatile("s_waitcnt vmcnt(6)" ::: "memory");
    else    asm volatile("s_waitcnt vmcnt(0)" ::: "memory");
    PH_MID(); QUAD(4, 0, bLo); PH_END();

    // ======== tile b = 2i+1 (buf1) ========
    // P5 (Alo,Blo)
    RD_A(32768 + aLoOff); RD_B(bLo, 32768 + bLoOff);
    if (go) STAGE_A(c, 1, 0);                     // buf0.Ah1 freed @P3
    PH_MID(); QUAD(0, 0, bLo); PH_END();
    // P6 (Alo,Bhi)
    RD_B(bHi, 32768 + bHiOff);
    if (go) STAGE_A(d, 0, 1);                     // buf1.Ah0 freed @P5
    PH_MID(); QUAD(0, 2, bHi); PH_END();
    // P7 (Ahi,Bhi)
    RD_A(32768 + aHiOff);
    if (go) STAGE_B(d, 0, 1);                     // buf1.Bh0 freed @P5
    PH_MID(); QUAD(4, 2, bHi); PH_END();
    // P8 (Ahi,Blo)
    if (go) STAGE_B(d, 1, 1);                     // buf1.Bh1 freed @P6
    if (go) asm volatile("s_waitcnt vmcnt(6)" ::: "memory");
    else    asm volatile("s_waitcnt vmcnt(0)" ::: "memory");
    PH_MID(); QUAD(4, 0, bLo); PH_END();
  }

  // ---- epilogue: per-wave XOR-swizzled LDS staging (4KB) -> coalesced stores ----
  __syncthreads();
  float bias4[4];
  if (HAS_BIAS) {
    #pragma unroll
    for (int nf = 0; nf < 4; ++nf) {
      const int pc = (nf < 2) ? (wn * 32 + nf * 16) : (128 + wn * 32 + (nf - 2) * 16);
      bias4[nf] = bias[bn + pc + (l & 15)];
    }
  }
  float* fl = (float*)lds + w * 1024;
  const long long cbase = (long long)blockIdx.z * sCb;
  const int q = l >> 4;
  const int cl = (l & 15) * 4;                                   // logical col of store
  const int physcol = (cl < 32) ? (wn * 32 + cl) : (128 + wn * 32 + (cl - 32));
  #pragma unroll
  for (int mf = 0; mf < 8; ++mf) {
    #pragma unroll
    for (int nf = 0; nf < 4; ++nf) {
      #pragma unroll
      for (int r = 0; r < 4; ++r) {
        float v = acc[mf][nf][r] * scale;
        if (HAS_BIAS) v += bias4[nf];
        if (RELU) v = fmaxf(v, 0.f);
        fl[(q * 4 + r) * 64 + ((((l & 15) + nf * 16)) ^ (q << 4))] = v;
      }
    }
    asm volatile("s_waitcnt lgkmcnt(0)" ::: "memory");
    const int rowb = (mf < 4) ? (wm * 64 + mf * 16) : (128 + wm * 64 + (mf - 4) * 16);
    #pragma unroll
    for (int p = 0; p < 4; ++p) {
      f32x4 v = *(const f32x4*)(fl + (p * 4 + q) * 64 + (cl ^ (p << 4)));
      const long long row = bm + rowb + p * 4 + q;
      const long long cidx = cbase + row * ldc + bn + physcol;
      if (OUT_BF16) {
        u16x4 o; o.x = f2bf(v.x); o.y = f2bf(v.y); o.z = f2bf(v.z); o.w = f2bf(v.w);
        *(u16x4*)((u16*)C + cidx) = o;
      } else {
        *(f32x4*)((float*)C + cidx) = v;
      }
    }
    asm volatile("s_waitcnt lgkmcnt(0)" ::: "memory");
  }
#undef STG
#undef STAGE_A
#undef STAGE_B
#undef RD_A
#undef RD_B
#undef QUAD
#undef PH_MID
#undef PH_END
}

// =====================================================================================
// gemm128: BM=128, BN=256, BK=32, 48KB LDS, __launch_bounds__(512,4) -> 2 blocks/CU.
// (512,6) PROVEN BAD round 6: forces VGPR<=85 -> acc spills, WRITE_SIZE 65MB->927MB.
// =====================================================================================
template<bool RELU, bool OUT_BF16, bool HAS_BIAS>
__global__ __launch_bounds__(512, 4)
void gemm128(const u16* __restrict__ A, long long sAb, int lda,
             const u16* __restrict__ Bt, long long sBb, int ldb,
             const float* __restrict__ bias,
             void* __restrict__ C, long long sCb, int ldc,
             int K, float scale)
{
  __shared__ __align__(16) u16 lds[24576];  // 48KB

  const int tid = threadIdx.x;
  const int w = tid >> 6, l = tid & 63;
  const int wm = w >> 2, wn = w & 3;

  const int gx = gridDim.x;
  const int nwg = gx * gridDim.y;
  const int f = blockIdx.x + gx * blockIdx.y;
  const int fs = (f & 7) * (nwg >> 3) + (f >> 3);
  const int bx = fs % gx, by = fs / gx;

  const long long bm = (long long)by * 128;
  const long long bn = (long long)bx * 256;
  const u16* Ab = A + (long long)blockIdx.z * sAb;
  const u16* Btb = Bt + (long long)blockIdx.z * sBb;

  const int ia = w * 64 + l;
  const int ra = ia >> 2;
  const int ga = (ia & 3) ^ ((ra >> 1) & 3);
  const u16* pA  = Ab  + (bm + ra) * (long long)lda + ga * 8;
  const u16* pB0 = Btb + (bn + ra) * (long long)ldb + ga * 8;
  const u16* pB1 = Btb + (bn + 128 + ra) * (long long)ldb + ga * 8;
  u16* dA  = lds + w * 512;
  u16* dB0 = lds + 4096 + w * 512;
  u16* dB1 = lds + 8192 + w * 512;

  const int swz = ((l >> 4) ^ (((l & 15) >> 1) & 3)) << 3;
  const int aOff = (wm * 64 + (l & 15)) * 32 + swz;
  const int bOff = 4096 + (wn * 64 + (l & 15)) * 32 + swz;

  f32x4 acc[4][4] = {};
  const int NKT = K >> 5;

  gload_lds16(pA, dA);        gload_lds16(pB0, dB0);        gload_lds16(pB1, dB1);
  gload_lds16(pA + 32, dA + 12288); gload_lds16(pB0 + 32, dB0 + 12288); gload_lds16(pB1 + 32, dB1 + 12288);

  for (int kt = 0; kt < NKT; ++kt) {
    if (kt + 1 < NKT) asm volatile("s_waitcnt vmcnt(3)" ::: "memory");
    else              asm volatile("s_waitcnt vmcnt(0)" ::: "memory");
    __builtin_amdgcn_s_barrier();
    __builtin_amdgcn_sched_barrier(0);

    const u16* bufc = lds + (kt & 1) * 12288;
    bf16x8 aF[4], bF[4];
    #pragma unroll
    for (int mf = 0; mf < 4; ++mf) aF[mf] = *(const bf16x8*)(bufc + aOff + mf * 512);
    #pragma unroll
    for (int nf = 0; nf < 4; ++nf) bF[nf] = *(const bf16x8*)(bufc + bOff + nf * 512);
    asm volatile("s_waitcnt lgkmcnt(0)" ::: "memory");
    __builtin_amdgcn_s_barrier();
    __builtin_amdgcn_sched_barrier(0);

    if (kt + 2 < NKT) {
      u16* d = lds + (kt & 1) * 12288 + w * 512;
      const long long ko = (long long)(kt + 2) * 32;
      gload_lds16(pA + ko, d);
      gload_lds16(pB0 + ko, d + 4096);
      gload_lds16(pB1 + ko, d + 8192);
    }
    __builtin_amdgcn_s_setprio(1);
    #pragma unroll
    for (int mf = 0; mf < 4; ++mf)
      #pragma unroll
      for (int nf = 0; nf < 4; ++nf)
        acc[mf][nf] = MFMA16(aF[mf], bF[nf], acc[mf][nf]);
    __builtin_amdgcn_s_setprio(0);
  }

  float bias4[4];
  if (HAS_BIAS) {
    #pragma unroll
    for (int nf = 0; nf < 4; ++nf) bias4[nf] = bias[bn + wn * 64 + (l & 15) + nf * 16];
  }
  float* fl = (float*)lds + w * 1024;
  const long long cbase = (long long)blockIdx.z * sCb;
  const int q = l >> 4;
  #pragma unroll
  for (int mf = 0; mf < 4; ++mf) {
    #pragma unroll
    for (int nf = 0; nf < 4; ++nf) {
      #pragma unroll
      for (int r = 0; r < 4; ++r) {
        float v = acc[mf][nf][r] * scale;
        if (HAS_BIAS) v += bias4[nf];
        if (RELU) v = fmaxf(v, 0.f);
        fl[(q * 4 + r) * 64 + ((((l & 15) + nf * 16)) ^ (q << 4))] = v;
      }
    }
    asm volatile("s_waitcnt lgkmcnt(0)" ::: "memory");
    #pragma unroll
    for (int p = 0; p < 4; ++p) {
      f32x4 v = *(const f32x4*)(fl + (p * 4 + q) * 64 + (((l & 15) * 4) ^ (p << 4)));
      const long long row = bm + wm * 64 + mf * 16 + p * 4 + q;
      const long long cidx = cbase + row * ldc + bn + wn * 64 + (l & 15) * 4;
      if (OUT_BF16) {
        u16x4 o; o.x = f2bf(v.x); o.y = f2bf(v.y); o.z = f2bf(v.z); o.w = f2bf(v.w);
        *(u16x4*)((u16*)C + cidx) = o;
      } else {
        *(f32x4*)((float*)C + cidx) = v;
      }
    }
    asm volatile("s_waitcnt lgkmcnt(0)" ::: "memory");
  }
}

// ---------------- transpose fp32 [inR][inC] -> bf16 [outR][outC], out[r][c]=in[c][r], zero-padded ----------------
__global__ void transpose_cast_pad(const float* __restrict__ in, int inR, int inC,
                                   u16* __restrict__ out, int outR, int outC)
{
  __shared__ float tile[32][33];
  const int c0 = blockIdx.x * 32;
  const int r0 = blockIdx.y * 32;
  const int tx = threadIdx.x, ty = threadIdx.y;
  for (int i = ty; i < 32; i += 8) {
    int r = r0 + i, c = c0 + tx;
    tile[i][tx] = (r < inR && c < inC) ? in[(long long)r * inC + c] : 0.f;
  }
  __syncthreads();
  for (int i = ty; i < 32; i += 8) {
    int orow = c0 + i, ocol = r0 + tx;
    if (orow < outR && ocol < outC)
      out[(long long)orow * outC + ocol] = f2bf(tile[tx][i]);
  }
}

// ---------------- transpose bf16 [R][C] (stride ldi) -> [C][R] (stride ldo), batched ----------------
__global__ void transpose_bf16_k(const u16* __restrict__ in, long long sIb, int ldi,
                                 u16* __restrict__ out, long long sOb, int ldo)
{
  __shared__ u16 tile[32][33];
  const u16* inp = in + (long long)blockIdx.z * sIb;
  u16* outp = out + (long long)blockIdx.z * sOb;
  const int r0 = blockIdx.y * 32, c0 = blockIdx.x * 32;
  const int tx = threadIdx.x, ty = threadIdx.y;
  for (int i = ty; i < 32; i += 8)
    tile[i][tx] = inp[(long long)(r0 + i) * ldi + c0 + tx];
  __syncthreads();
  for (int i = ty; i < 32; i += 8)
    outp[(long long)(c0 + i) * ldo + r0 + tx] = tile[tx][i];
}

__global__ void cast_f32_bf16_k(const float* __restrict__ in, u16* __restrict__ out, int n4)
{
  int i = blockIdx.x * blockDim.x + threadIdx.x;
  if (i >= n4) return;
  float4 v = ((const float4*)in)[i];
  u16x4 o; o.x = f2bf(v.x); o.y = f2bf(v.y); o.z = f2bf(v.z); o.w = f2bf(v.w);
  ((u16x4*)out)[i] = o;
}

__global__ void prep_bias_k(const float* __restrict__ bmlp, const float* __restrict__ bq,
                            const float* __restrict__ bk, const float* __restrict__ bv,
                            const float* __restrict__ bm,
                            float* __restrict__ outMlp, float* __restrict__ outQkvm)
{
  int i = blockIdx.x * 256 + threadIdx.x;
  if (i < 768) outMlp[i] = (i < 568) ? bmlp[i] : 0.f;
  if (i < 4096) {
    const float* s = (i < 1024) ? bq : (i < 2048) ? bk : (i < 3072) ? bv : bm;
    outQkvm[i] = s[i & 1023];
  }
}

// in-place row softmax over 2048 bf16 elements; one block per row
__global__ __launch_bounds__(256)
void softmax_rows_k(u16* __restrict__ sc)
{
  __shared__ float red[8];
  const long long base = (long long)blockIdx.x * 2048;
  const int t = threadIdx.x, wave = t >> 6, lane = t & 63;
  u16x8 v8 = *((const u16x8*)(sc + base + t * 8));
  float v[8];
  #pragma unroll
  for (int j = 0; j < 8; ++j) v[j] = bf2f(v8[j]);
  float m = v[0];
  #pragma unroll
  for (int j = 1; j < 8; ++j) m = fmaxf(m, v[j]);
  #pragma unroll
  for (int off = 32; off > 0; off >>= 1) m = fmaxf(m, __shfl_xor(m, off, 64));
  if (lane == 0) red[wave] = m;
  __syncthreads();
  m = fmaxf(fmaxf(red[0], red[1]), fmaxf(red[2], red[3]));
  float s = 0.f;
  #pragma unroll
  for (int j = 0; j < 8; ++j) { v[j] = __expf(v[j] - m); s += v[j]; }
  #pragma unroll
  for (int off = 32; off > 0; off >>= 1) s += __shfl_xor(s, off, 64);
  if (lane == 0) red[4 + wave] = s;
  __syncthreads();
  s = red[4] + red[5] + red[6] + red[7];
  float inv = 1.f / s;
  u16x8 o;
  #pragma unroll
  for (int j = 0; j < 8; ++j) o[j] = f2bf(v[j] * inv);
  *((u16x8*)(sc + base + t * 8)) = o;
}

// x1 = LN(a_bf16 + b_bf16) * gamma + beta -> bf16 out. One block per 1024-wide row.
__global__ __launch_bounds__(256)
void add_ln_k(const u16* __restrict__ a, int lda, const u16* __restrict__ b,
              const float* __restrict__ gamma, const float* __restrict__ beta,
              u16* __restrict__ out)
{
  __shared__ float red[8];
  const long long row = blockIdx.x;
  const int t = threadIdx.x, wave = t >> 6, lane = t & 63;
  u16x4 av = *((const u16x4*)(a + row * lda + t * 4));
  u16x4 bv = *((const u16x4*)(b + row * 1024 + t * 4));
  float z[4] = { bf2f(av.x) + bf2f(bv.x), bf2f(av.y) + bf2f(bv.y),
                 bf2f(av.z) + bf2f(bv.z), bf2f(av.w) + bf2f(bv.w) };
  float s = z[0] + z[1] + z[2] + z[3];
  float ss = z[0]*z[0] + z[1]*z[1] + z[2]*z[2] + z[3]*z[3];
  #pragma unroll
  for (int off = 32; off > 0; off >>= 1) { s += __shfl_xor(s, off, 64); ss += __shfl_xor(ss, off, 64); }
  if (lane == 0) { red[wave] = s; red[4 + wave] = ss; }
  __syncthreads();
  s = red[0] + red[1] + red[2] + red[3];
  ss = red[4] + red[5] + red[6] + red[7];
  float mu = s * (1.f / 1024.f);
  float var = ss * (1.f / 1024.f) - mu * mu;
  float rstd = rsqrtf(var + 1e-5f);
  float4 g = ((const float4*)gamma)[t];
  float4 be = ((const float4*)beta)[t];
  u16x4 o;
  o.x = f2bf((z[0] - mu) * rstd * g.x + be.x);
  o.y = f2bf((z[1] - mu) * rstd * g.y + be.y);
  o.z = f2bf((z[2] - mu) * rstd * g.z + be.z);
  o.w = f2bf((z[3] - mu) * rstd * g.w + be.w);
  *((u16x4*)(out + row * 1024 + t * 4)) = o;
}

// out = relu(LN(a_bf16 + b_bf16) * gamma + beta) -> f32. One block per 1024-wide row.
__global__ __launch_bounds__(256)
void add_ln_relu_k(const u16* __restrict__ a, const u16* __restrict__ b,
                   const float* __restrict__ gamma, const float* __restrict__ beta,
                   float* __restrict__ out)
{
  __shared__ float red[8];
  const long long row = blockIdx.x;
  const int t = threadIdx.x, wave = t >> 6, lane = t & 63;
  u16x4 av = *((const u16x4*)(a + row * 1024 + t * 4));
  u16x4 bv = *((const u16x4*)(b + row * 1024 + t * 4));
  float z[4] = { bf2f(av.x) + bf2f(bv.x), bf2f(av.y) + bf2f(bv.y),
                 bf2f(av.z) + bf2f(bv.z), bf2f(av.w) + bf2f(bv.w) };
  float s = z[0] + z[1] + z[2] + z[3];
  float ss = z[0]*z[0] + z[1]*z[1] + z[2]*z[2] + z[3]*z[3];
  #pragma unroll
  for (int off = 32; off > 0; off >>= 1) { s += __shfl_xor(s, off, 64); ss += __shfl_xor(ss, off, 64); }
  if (lane == 0) { red[wave] = s; red[4 + wave] = ss; }
  __syncthreads();
  s = red[0] + red[1] + red[2] + red[3];
  ss = red[4] + red[5] + red[6] + red[7];
  float mu = s * (1.f / 1024.f);
  float var = ss * (1.f / 1024.f) - mu * mu;
  float rstd = rsqrtf(var + 1e-5f);
  float4 g = ((const float4*)gamma)[t];
  float4 be = ((const float4*)beta)[t];
  float4 o;
  o.x = fmaxf((z[0] - mu) * rstd * g.x + be.x, 0.f);
  o.y = fmaxf((z[1] - mu) * rstd * g.y + be.y, 0.f);
  o.z = fmaxf((z[2] - mu) * rstd * g.z + be.z, 0.f);
  o.w = fmaxf((z[3] - mu) * rstd * g.w + be.w, 0.f);
  ((float4*)(out + row * 1024))[t] = o;
}

extern "C" void kernel_launch(void* const* d_in, const int* in_sizes, int n_in,
                              void* d_out, int out_size, void* d_ws, size_t ws_size,
                              hipStream_t stream)
{
  const float* x    = (const float*)d_in[0];
  const float* wmlp = (const float*)d_in[1];
  const float* bmlp = (const float*)d_in[2];
  const float* wq   = (const float*)d_in[3];  const float* bq  = (const float*)d_in[4];
  const float* wk   = (const float*)d_in[5];  const float* bk  = (const float*)d_in[6];
  const float* wv   = (const float*)d_in[7];  const float* bv  = (const float*)d_in[8];
  const float* wm   = (const float*)d_in[9];  const float* bm  = (const float*)d_in[10];
  const float* g1   = (const float*)d_in[11]; const float* be1 = (const float*)d_in[12];
  const float* wf1  = (const float*)d_in[13]; const float* bf1 = (const float*)d_in[14];
  const float* wf2  = (const float*)d_in[15]; const float* bf2 = (const float*)d_in[16];
  const float* g2   = (const float*)d_in[17]; const float* be2 = (const float*)d_in[18];

  // B=4, S=2048, IN_C=768, HID=568 (MLP-N pad 768, QKVM-K pad 640), OUT_C=1024.
  char* ws = (char*)d_ws;
  size_t off = 0;
  auto alloc = [&](size_t bytes) { char* p = ws + off; off += (bytes + 255) & ~(size_t)255; return p; };
  u16*  W_MLP_T  = (u16*)alloc((size_t)768 * 768 * 2);     // [768][768]
  u16*  W_QKVM_T = (u16*)alloc((size_t)4096 * 640 * 2);    // [4096][640]
  u16*  W_F1_T   = (u16*)alloc((size_t)1024 * 1024 * 2);
  u16*  W_F2_T   = (u16*)alloc((size_t)1024 * 1024 * 2);
  float* B_MLP   = (float*)alloc(768 * 4);
  float* B_QKVM  = (float*)alloc(4096 * 4);
  u16*  XBF      = (u16*)alloc((size_t)8192 * 768 * 2);
  u16*  H        = (u16*)alloc((size_t)8192 * 768 * 2);    // relu(mlp), cols 568..767 = 0
  u16*  QKVM     = (u16*)alloc((size_t)8192 * 4096 * 2);   // q|k|v|m, ld 4096
  u16*  VT       = (u16*)alloc((size_t)4 * 1024 * 2048 * 2);
  u16*  SC       = (u16*)alloc((size_t)4 * 2048 * 2048 * 2);
  u16*  AO       = (u16*)alloc((size_t)8192 * 1024 * 2);   // attn_out (bf16)
  u16*  X1       = (u16*)alloc((size_t)8192 * 1024 * 2);
  u16*  T  = QKVM;                                          // ffn hidden bf16 [8192][1024]
  u16*  F  = QKVM + (size_t)8192 * 1024;                    // ffn out bf16 [8192][1024]

  hipFuncSetAttribute((const void*)gemm8q<false, true, true >, hipFuncAttributeMaxDynamicSharedMemorySize, 131072);
  hipFuncSetAttribute((const void*)gemm8q<false, true, false>, hipFuncAttributeMaxDynamicSharedMemorySize, 131072);

  dim3 tb(32, 8);

  // 1) cast x -> bf16
  cast_f32_bf16_k<<<(8192 * 768 / 4 + 255) / 256, 256, 0, stream>>>(x, XBF, 8192 * 768 / 4);
  // 2) weight transposes (fp32 [K][N] -> bf16 [Npad][Kpad])
  transpose_cast_pad<<<dim3(24, 24), tb, 0, stream>>>(wmlp, 768, 568, W_MLP_T, 768, 768);
  transpose_cast_pad<<<dim3(32, 20), tb, 0, stream>>>(wq, 568, 1024, W_QKVM_T + (size_t)0 * 1024 * 640, 1024, 640);
  transpose_cast_pad<<<dim3(32, 20), tb, 0, stream>>>(wk, 568, 1024, W_QKVM_T + (size_t)1 * 1024 * 640, 1024, 640);
  transpose_cast_pad<<<dim3(32, 20), tb, 0, stream>>>(wv, 568, 1024, W_QKVM_T + (size_t)2 * 1024 * 640, 1024, 640);
  transpose_cast_pad<<<dim3(32, 20), tb, 0, stream>>>(wm, 568, 1024, W_QKVM_T + (size_t)3 * 1024 * 640, 1024, 640);
  transpose_cast_pad<<<dim3(32, 32), tb, 0, stream>>>(wf1, 1024, 1024, W_F1_T, 1024, 1024);
  transpose_cast_pad<<<dim3(32, 32), tb, 0, stream>>>(wf2, 1024, 1024, W_F2_T, 1024, 1024);
  prep_bias_k<<<16, 256, 0, stream>>>(bmlp, bq, bk, bv, bm, B_MLP, B_QKVM);

  // 3) h = relu(x @ w_mlp + b)   M=8192 N=768 K=768  (gemm128, grid 3x64=192)
  gemm128<true, true, true><<<dim3(3, 64, 1), 512, 0, stream>>>(
      XBF, 0, 768, W_MLP_T, 0, 768, B_MLP, H, 0, 768, 768, 1.0f);
  // 4) qkvm = h @ [wq|wk|wv|wm] + b   M=8192 N=4096 K=640  (gemm8q, grid 16x32=512)
  gemm8q<false, true, true><<<dim3(16, 32, 1), 512, 131072, stream>>>(
      H, 0, 768, W_QKVM_T, 0, 640, B_QKVM, QKVM, 0, 4096, 640, 1.0f);
  // 5) v^T per batch: [2048][1024] (ld 4096) -> [1024][2048]
  transpose_bf16_k<<<dim3(32, 64, 4), tb, 0, stream>>>(
      QKVM + 2048, (long long)2048 * 4096, 4096, VT, (long long)1024 * 2048, 2048);
  // 6) scores = q @ k^T * 1/32   per batch M=N=2048 K=1024  (gemm8q, grid 8x8x4)
  gemm8q<false, true, false><<<dim3(8, 8, 4), 512, 131072, stream>>>(
      QKVM, (long long)2048 * 4096, 4096, QKVM + 1024, (long long)2048 * 4096, 4096,
      nullptr, SC, (long long)2048 * 2048, 2048, 1024, 0.03125f);
  // 7) P = softmax(scores) in-place
  softmax_rows_k<<<8192, 256, 0, stream>>>(SC);
  // 8) attn_out = P @ v   per batch M=2048 N=1024 K=2048  (gemm128, grid 4x16x4=256)
  gemm128<false, true, false><<<dim3(4, 16, 4), 512, 0, stream>>>(
      SC, (long long)2048 * 2048, 2048, VT, (long long)1024 * 2048, 2048,
      nullptr, AO, (long long)2048 * 1024, 1024, 2048, 1.0f);
  // 9) x1 = LN(m + attn_out)
  add_ln_k<<<8192, 256, 0, stream>>>(QKVM + 3072, 4096, AO, g1, be1, X1);
  // 10) t = relu(x1 @ wf1 + bf1)   (gemm128, grid 4x64=256)
  gemm128<true, true, true><<<dim3(4, 64, 1), 512, 0, stream>>>(
      X1, 0, 1024, W_F1_T, 0, 1024, bf1, T, 0, 1024, 1024, 1.0f);
  // 11) f = t @ wf2 + bf2 (bf16)
  gemm128<false, true, true><<<dim3(4, 64, 1), 512, 0, stream>>>(
      T, 0, 1024, W_F2_T, 0, 1024, bf2, F, 0, 1024, 1024, 1.0f);
  // 12) out = relu(LN(x1 + f))
  add_ln_relu_k<<<8192, 256, 0, stream>>>(X1, F, g2, be2, (float*)d_out);
}

// Round 9
// 253.418 us; speedup vs baseline: 1.0847x; 1.0847x over previous
//
#include <hip/hip_runtime.h>

#define DI __device__ __forceinline__

typedef unsigned short u16;
typedef __attribute__((__ext_vector_type__(8))) __bf16 bf16x8;
typedef __attribute__((__ext_vector_type__(4))) float f32x4;
typedef __attribute__((__ext_vector_type__(4))) unsigned short u16x4;
typedef __attribute__((__ext_vector_type__(8))) unsigned short u16x8;

DI float bf2f(u16 u) { union { unsigned int i; float f; } x; x.i = ((unsigned int)u) << 16; return x.f; }
DI u16 f2bf(float f) {
  union { float f; unsigned int i; } x; x.f = f;
  unsigned int r = x.i + 0x7fffu + ((x.i >> 16) & 1u);
  return (u16)(r >> 16);
}

// async global->LDS, 16B per lane; LDS dest = wave-uniform base + lane*16
DI void gload_lds16(const void* g, void* lds) {
  __builtin_amdgcn_global_load_lds((const __attribute__((address_space(1))) unsigned int*)g,
                                   (__attribute__((address_space(3))) unsigned int*)lds, 16, 0, 0);
}

#define MFMA16(a, b, c) __builtin_amdgcn_mfma_f32_16x16x32_bf16((a), (b), (c), 0, 0, 0)

// =====================================================================================
// gemm256v2: C[M,N] = A[M,K] @ Bt[N,K]^T * scale + bias   (proven best: 841 TF)
// BM=BN=256, BK=64. 8 waves (2M x 4N), wave tile 128x64 (acc[8][4]).
// LDS: 2 buffers x 64KB = 128KB dynamic. Counted vmcnt(2)/vmcnt(8), never cold drain.
// k-granule XOR LDS layout; linear gload_lds dest, pre-permuted GLOBAL source (rule 21).
// Epilogue XOR-swizzled LDS staging -> coalesced 16B stores.
// Requires M%256==0, N%256==0, K%64==0. grid (N/256, M/256, z); (gx*gy)%8==0.
// =====================================================================================
template<bool RELU, bool OUT_BF16, bool HAS_BIAS>
__global__ __launch_bounds__(512, 2)
void gemm256v2(const u16* __restrict__ A, long long sAb, int lda,
               const u16* __restrict__ Bt, long long sBb, int ldb,
               const float* __restrict__ bias,
               void* __restrict__ C, long long sCb, int ldc,
               int K, float scale)
{
  extern __shared__ __align__(16) u16 lds[];

  const int tid = threadIdx.x;
  const int w = tid >> 6, l = tid & 63;
  const int wm = w >> 2, wn = w & 3;

  const int gx = gridDim.x;
  const int nwg = gx * gridDim.y;
  const int f = blockIdx.x + gx * blockIdx.y;
  const int fs = (f & 7) * (nwg >> 3) + (f >> 3);
  const int bx = fs % gx, by = fs / gx;

  const long long bm = (long long)by * 256;
  const long long bn = (long long)bx * 256;
  const u16* Ab = A + (long long)blockIdx.z * sAb;
  const u16* Btb = Bt + (long long)blockIdx.z * sBb;

  const int trow = tid >> 3;
  const int tg = (tid & 7) ^ (trow & 7);
  const u16* sA = Ab + (bm + trow) * (long long)lda + tg * 8;
  const u16* sB = Btb + (bn + trow) * (long long)ldb + tg * 8;
  const long long la64 = (long long)64 * lda, lb64 = (long long)64 * ldb;

  const int swz0 = (((l >> 4) ^ (l & 7))) * 8;
  const int aB = (wm * 128 + (l & 15)) * 64;
  const int bB = 16384 + (wn * 64 + (l & 15)) * 64;

  f32x4 acc[8][4] = {};
  const int NKT = K >> 6;

  {
    u16* sp = lds;
    gload_lds16(sA, sp + w * 512);
    gload_lds16(sA + 2 * la64, sp + 8192 + w * 512);
    gload_lds16(sB, sp + 16384 + w * 512);
    gload_lds16(sB + lb64, sp + 20480 + w * 512);
    gload_lds16(sB + 2 * lb64, sp + 24576 + w * 512);
    gload_lds16(sB + 3 * lb64, sp + 28672 + w * 512);
    gload_lds16(sA + la64, sp + 4096 + w * 512);
    gload_lds16(sA + 3 * la64, sp + 12288 + w * 512);
  }

  for (int kt = 0; kt < NKT; ++kt) {
    const u16* bp = lds + (kt & 1) * 32768;
    u16* sp = lds + ((kt & 1) ^ 1) * 32768;
    const bool st = (kt + 1) < NKT;
    const long long ko = (long long)(kt + 1) * 64;

    asm volatile("s_waitcnt vmcnt(2)" ::: "memory");
    __builtin_amdgcn_s_barrier();

    if (st) {
      gload_lds16(sA + ko, sp + w * 512);
      gload_lds16(sA + 2 * la64 + ko, sp + 8192 + w * 512);
      gload_lds16(sB + ko, sp + 16384 + w * 512);
      gload_lds16(sB + lb64 + ko, sp + 20480 + w * 512);
      gload_lds16(sB + 2 * lb64 + ko, sp + 24576 + w * 512);
      gload_lds16(sB + 3 * lb64 + ko, sp + 28672 + w * 512);
    }

    bf16x8 bF[4][2], aF[4][2];
    #pragma unroll
    for (int nf = 0; nf < 4; ++nf) {
      bF[nf][0] = *(const bf16x8*)(bp + bB + nf * 1024 + swz0);
      bF[nf][1] = *(const bf16x8*)(bp + bB + nf * 1024 + (swz0 ^ 32));
    }
    #pragma unroll
    for (int mf = 0; mf < 4; ++mf) {
      aF[mf][0] = *(const bf16x8*)(bp + aB + mf * 1024 + swz0);
      aF[mf][1] = *(const bf16x8*)(bp + aB + mf * 1024 + (swz0 ^ 32));
    }
    if (st) {
      gload_lds16(sA + la64 + ko, sp + 4096 + w * 512);
      gload_lds16(sA + 3 * la64 + ko, sp + 12288 + w * 512);
    }
    __builtin_amdgcn_s_setprio(1);
    #pragma unroll
    for (int mf = 0; mf < 4; ++mf)
      #pragma unroll
      for (int nf = 0; nf < 4; ++nf) {
        acc[mf][nf] = MFMA16(aF[mf][0], bF[nf][0], acc[mf][nf]);
        acc[mf][nf] = MFMA16(aF[mf][1], bF[nf][1], acc[mf][nf]);
      }
    __builtin_amdgcn_s_setprio(0);

    if (st) asm volatile("s_waitcnt vmcnt(8)" ::: "memory");
    else    asm volatile("s_waitcnt vmcnt(0)" ::: "memory");
    __builtin_amdgcn_s_barrier();

    #pragma unroll
    for (int mf = 0; mf < 4; ++mf) {
      aF[mf][0] = *(const bf16x8*)(bp + aB + (mf + 4) * 1024 + swz0);
      aF[mf][1] = *(const bf16x8*)(bp + aB + (mf + 4) * 1024 + (swz0 ^ 32));
    }
    __builtin_amdgcn_s_setprio(1);
    #pragma unroll
    for (int mf = 0; mf < 4; ++mf)
      #pragma unroll
      for (int nf = 0; nf < 4; ++nf) {
        acc[mf + 4][nf] = MFMA16(aF[mf][0], bF[nf][0], acc[mf + 4][nf]);
        acc[mf + 4][nf] = MFMA16(aF[mf][1], bF[nf][1], acc[mf + 4][nf]);
      }
    __builtin_amdgcn_s_setprio(0);
  }

  __syncthreads();
  float bias4[4];
  if (HAS_BIAS) {
    #pragma unroll
    for (int nf = 0; nf < 4; ++nf) bias4[nf] = bias[bn + wn * 64 + (l & 15) + nf * 16];
  }
  float* fl = (float*)lds + w * 1024;
  const long long cbase = (long long)blockIdx.z * sCb;
  const int q = l >> 4;
  #pragma unroll
  for (int mf = 0; mf < 8; ++mf) {
    #pragma unroll
    for (int nf = 0; nf < 4; ++nf) {
      #pragma unroll
      for (int r = 0; r < 4; ++r) {
        float v = acc[mf][nf][r] * scale;
        if (HAS_BIAS) v += bias4[nf];
        if (RELU) v = fmaxf(v, 0.f);
        fl[(q * 4 + r) * 64 + ((((l & 15) + nf * 16)) ^ (q << 4))] = v;
      }
    }
    asm volatile("s_waitcnt lgkmcnt(0)" ::: "memory");
    #pragma unroll
    for (int p = 0; p < 4; ++p) {
      f32x4 v = *(const f32x4*)(fl + (p * 4 + q) * 64 + (((l & 15) * 4) ^ (p << 4)));
      const long long row = bm + wm * 128 + mf * 16 + p * 4 + q;
      const long long cidx = cbase + row * ldc + bn + wn * 64 + (l & 15) * 4;
      if (OUT_BF16) {
        u16x4 o; o.x = f2bf(v.x); o.y = f2bf(v.y); o.z = f2bf(v.z); o.w = f2bf(v.w);
        *(u16x4*)((u16*)C + cidx) = o;
      } else {
        *(f32x4*)((float*)C + cidx) = v;
      }
    }
    asm volatile("s_waitcnt lgkmcnt(0)" ::: "memory");
  }
}

// =====================================================================================
// gemm256n128: v2 template with BN=128 (full-grid fill for N=1024-class GEMMs).
// BM=256, BN=128, BK=64. 8 waves (2M x 4N), wave tile 128x32 (acc[8][2]).
// LDS: 2 buffers x 48KB = 96KB dynamic. 6 staging issues/K-tile: early-4 {A0,A2,B0,B1},
// late-2 {A1,A3}. Counted vmcnt(2) top / vmcnt(6) mid. Same k-granule XOR layout.
// Requires M%256==0, N%128==0, K%64==0. grid (N/128, M/256, z); (gx*gy)%8==0.
// =====================================================================================
template<bool RELU, bool OUT_BF16, bool HAS_BIAS>
__global__ __launch_bounds__(512, 2)
void gemm256n128(const u16* __restrict__ A, long long sAb, int lda,
                 const u16* __restrict__ Bt, long long sBb, int ldb,
                 const float* __restrict__ bias,
                 void* __restrict__ C, long long sCb, int ldc,
                 int K, float scale)
{
  extern __shared__ __align__(16) u16 lds[];

  const int tid = threadIdx.x;
  const int w = tid >> 6, l = tid & 63;
  const int wm = w >> 2, wn = w & 3;

  const int gx = gridDim.x;
  const int nwg = gx * gridDim.y;
  const int f = blockIdx.x + gx * blockIdx.y;
  const int fs = (f & 7) * (nwg >> 3) + (f >> 3);
  const int bx = fs % gx, by = fs / gx;

  const long long bm = (long long)by * 256;
  const long long bn = (long long)bx * 128;
  const u16* Ab = A + (long long)blockIdx.z * sAb;
  const u16* Btb = Bt + (long long)blockIdx.z * sBb;

  const int trow = tid >> 3;
  const int tg = (tid & 7) ^ (trow & 7);
  const u16* gA = Ab + (bm + trow) * (long long)lda + tg * 8;
  const u16* gB = Btb + (bn + trow) * (long long)ldb + tg * 8;
  const long long la64 = (long long)64 * lda, lb64 = (long long)64 * ldb;

  const int swz0 = ((l >> 4) ^ (l & 7)) * 8;
  const int aB = (wm * 128 + (l & 15)) * 64;          // A region: [0, 16384) u16
  const int bB = 16384 + (wn * 32 + (l & 15)) * 64;   // B region: [16384, 24576) u16

  f32x4 acc[8][2] = {};
  const int NKT = K >> 6;

  // prologue: tile 0 -> buf0; early-4 then late-2
  gload_lds16(gA,            lds + w * 512);
  gload_lds16(gA + 2 * la64, lds + 8192 + w * 512);
  gload_lds16(gB,            lds + 16384 + w * 512);
  gload_lds16(gB + lb64,     lds + 20480 + w * 512);
  gload_lds16(gA + la64,     lds + 4096 + w * 512);
  gload_lds16(gA + 3 * la64, lds + 12288 + w * 512);

  for (int kt = 0; kt < NKT; ++kt) {
    const u16* bp = lds + (kt & 1) * 24576;
    u16* sp = lds + ((kt & 1) ^ 1) * 24576;
    const bool st = (kt + 1) < NKT;
    const long long ko = (long long)(kt + 1) * 64;

    asm volatile("s_waitcnt vmcnt(2)" ::: "memory");
    __builtin_amdgcn_s_barrier();

    if (st) {  // early-4 for next tile
      gload_lds16(gA + ko,            sp + w * 512);
      gload_lds16(gA + 2 * la64 + ko, sp + 8192 + w * 512);
      gload_lds16(gB + ko,            sp + 16384 + w * 512);
      gload_lds16(gB + lb64 + ko,     sp + 20480 + w * 512);
    }

    bf16x8 bF[2][2], aF[4][2];
    #pragma unroll
    for (int nf = 0; nf < 2; ++nf) {
      bF[nf][0] = *(const bf16x8*)(bp + bB + nf * 1024 + swz0);
      bF[nf][1] = *(const bf16x8*)(bp + bB + nf * 1024 + (swz0 ^ 32));
    }
    #pragma unroll
    for (int mf = 0; mf < 4; ++mf) {
      aF[mf][0] = *(const bf16x8*)(bp + aB + mf * 1024 + swz0);
      aF[mf][1] = *(const bf16x8*)(bp + aB + mf * 1024 + (swz0 ^ 32));
    }
    if (st) {  // late-2 for next tile
      gload_lds16(gA + la64 + ko,     sp + 4096 + w * 512);
      gload_lds16(gA + 3 * la64 + ko, sp + 12288 + w * 512);
    }
    __builtin_amdgcn_s_setprio(1);
    #pragma unroll
    for (int mf = 0; mf < 4; ++mf)
      #pragma unroll
      for (int nf = 0; nf < 2; ++nf) {
        acc[mf][nf] = MFMA16(aF[mf][0], bF[nf][0], acc[mf][nf]);
        acc[mf][nf] = MFMA16(aF[mf][1], bF[nf][1], acc[mf][nf]);
      }
    __builtin_amdgcn_s_setprio(0);

    if (st) asm volatile("s_waitcnt vmcnt(6)" ::: "memory");
    else    asm volatile("s_waitcnt vmcnt(0)" ::: "memory");
    __builtin_amdgcn_s_barrier();

    #pragma unroll
    for (int mf = 0; mf < 4; ++mf) {
      aF[mf][0] = *(const bf16x8*)(bp + aB + (mf + 4) * 1024 + swz0);
      aF[mf][1] = *(const bf16x8*)(bp + aB + (mf + 4) * 1024 + (swz0 ^ 32));
    }
    __builtin_amdgcn_s_setprio(1);
    #pragma unroll
    for (int mf = 0; mf < 4; ++mf)
      #pragma unroll
      for (int nf = 0; nf < 2; ++nf) {
        acc[mf + 4][nf] = MFMA16(aF[mf][0], bF[nf][0], acc[mf + 4][nf]);
        acc[mf + 4][nf] = MFMA16(aF[mf][1], bF[nf][1], acc[mf + 4][nf]);
      }
    __builtin_amdgcn_s_setprio(0);
  }

  // ---- epilogue: per-wave XOR-swizzled LDS staging (2KB) -> coalesced stores ----
  __syncthreads();
  float bias2[2];
  if (HAS_BIAS) {
    #pragma unroll
    for (int nf = 0; nf < 2; ++nf) bias2[nf] = bias[bn + wn * 32 + (l & 15) + nf * 16];
  }
  float* fl = (float*)lds + w * 512;
  const long long cbase = (long long)blockIdx.z * sCb;
  const int q = l >> 4;
  #pragma unroll
  for (int mf = 0; mf < 8; ++mf) {
    #pragma unroll
    for (int nf = 0; nf < 2; ++nf) {
      #pragma unroll
      for (int r = 0; r < 4; ++r) {
        float v = acc[mf][nf][r] * scale;
        if (HAS_BIAS) v += bias2[nf];
        if (RELU) v = fmaxf(v, 0.f);
        // row = q*4+r; X(row) = ((row>>2)&1)<<4 = (q&1)<<4
        fl[(q * 4 + r) * 32 + ((((l & 15) + nf * 16)) ^ ((q & 1) << 4))] = v;
      }
    }
    asm volatile("s_waitcnt lgkmcnt(0)" ::: "memory");
    #pragma unroll
    for (int p = 0; p < 2; ++p) {
      const int orow = p * 8 + (l >> 3);
      const int X = ((orow >> 2) & 1) << 4;
      f32x4 v = *(const f32x4*)(fl + orow * 32 + (((l & 7) * 4) ^ X));
      const long long row = bm + wm * 128 + mf * 16 + orow;
      const long long cidx = cbase + row * ldc + bn + wn * 32 + (l & 7) * 4;
      if (OUT_BF16) {
        u16x4 o; o.x = f2bf(v.x); o.y = f2bf(v.y); o.z = f2bf(v.z); o.w = f2bf(v.w);
        *(u16x4*)((u16*)C + cidx) = o;
      } else {
        *(f32x4*)((float*)C + cidx) = v;
      }
    }
    asm volatile("s_waitcnt lgkmcnt(0)" ::: "memory");
  }
}

// ---------------- transpose fp32 [inR][inC] -> bf16 [outR][outC], zero-padded ----------------
__global__ void transpose_cast_pad(const float* __restrict__ in, int inR, int inC,
                                   u16* __restrict__ out, int outR, int outC)
{
  __shared__ float tile[32][33];
  const int c0 = blockIdx.x * 32;
  const int r0 = blockIdx.y * 32;
  const int tx = threadIdx.x, ty = threadIdx.y;
  for (int i = ty; i < 32; i += 8) {
    int r = r0 + i, c = c0 + tx;
    tile[i][tx] = (r < inR && c < inC) ? in[(long long)r * inC + c] : 0.f;
  }
  __syncthreads();
  for (int i = ty; i < 32; i += 8) {
    int orow = c0 + i, ocol = r0 + tx;
    if (orow < outR && ocol < outC)
      out[(long long)orow * outC + ocol] = f2bf(tile[tx][i]);
  }
}

// ---------------- transpose64: bf16 [R][C] (ld ldi) -> [C][R] (ld ldo), batched ----------------
// 64x64 tile, 256 threads, u16x8 vector reads AND writes (128B per 8 lanes both sides).
__global__ __launch_bounds__(256)
void transpose64_k(const u16* __restrict__ in, long long sIb, int ldi,
                   u16* __restrict__ out, long long sOb, int ldo)
{
  __shared__ u16 tile[64][72];
  const u16* inp = in + (long long)blockIdx.z * sIb;
  u16* outp = out + (long long)blockIdx.z * sOb;
  const int r0 = blockIdx.y * 64, c0 = blockIdx.x * 64;
  const int t = threadIdx.x;
  const int jr = t >> 3, ch = t & 7;
  #pragma unroll
  for (int it = 0; it < 2; ++it) {
    const int row = jr + it * 32;
    u16x8 v = *(const u16x8*)(inp + (long long)(r0 + row) * ldi + c0 + ch * 8);
    *(u16x8*)(&tile[row][ch * 8]) = v;
  }
  __syncthreads();
  #pragma unroll
  for (int it = 0; it < 2; ++it) {
    const int orow = jr + it * 32;     // output row = input column
    u16x8 v;
    #pragma unroll
    for (int e = 0; e < 8; ++e) v[e] = tile[ch * 8 + e][orow];
    *(u16x8*)(outp + (long long)(c0 + orow) * ldo + r0 + ch * 8) = v;
  }
}

__global__ void cast_f32_bf16_k(const float* __restrict__ in, u16* __restrict__ out, int n4)
{
  int i = blockIdx.x * blockDim.x + threadIdx.x;
  if (i >= n4) return;
  float4 v = ((const float4*)in)[i];
  u16x4 o; o.x = f2bf(v.x); o.y = f2bf(v.y); o.z = f2bf(v.z); o.w = f2bf(v.w);
  ((u16x4*)out)[i] = o;
}

__global__ void prep_bias_k(const float* __restrict__ bmlp, const float* __restrict__ bq,
                            const float* __restrict__ bk, const float* __restrict__ bv,
                            const float* __restrict__ bm,
                            float* __restrict__ outMlp, float* __restrict__ outQkvm)
{
  int i = blockIdx.x * 256 + threadIdx.x;
  if (i < 768) outMlp[i] = (i < 568) ? bmlp[i] : 0.f;
  if (i < 4096) {
    const float* s = (i < 1024) ? bq : (i < 2048) ? bk : (i < 3072) ? bv : bm;
    outQkvm[i] = s[i & 1023];
  }
}

// in-place row softmax over 2048 bf16 elements; one block per row
__global__ __launch_bounds__(256)
void softmax_rows_k(u16* __restrict__ sc)
{
  __shared__ float red[8];
  const long long base = (long long)blockIdx.x * 2048;
  const int t = threadIdx.x, wave = t >> 6, lane = t & 63;
  u16x8 v8 = *((const u16x8*)(sc + base + t * 8));
  float v[8];
  #pragma unroll
  for (int j = 0; j < 8; ++j) v[j] = bf2f(v8[j]);
  float m = v[0];
  #pragma unroll
  for (int j = 1; j < 8; ++j) m = fmaxf(m, v[j]);
  #pragma unroll
  for (int off = 32; off > 0; off >>= 1) m = fmaxf(m, __shfl_xor(m, off, 64));
  if (lane == 0) red[wave] = m;
  __syncthreads();
  m = fmaxf(fmaxf(red[0], red[1]), fmaxf(red[2], red[3]));
  float s = 0.f;
  #pragma unroll
  for (int j = 0; j < 8; ++j) { v[j] = __expf(v[j] - m); s += v[j]; }
  #pragma unroll
  for (int off = 32; off > 0; off >>= 1) s += __shfl_xor(s, off, 64);
  if (lane == 0) red[4 + wave] = s;
  __syncthreads();
  s = red[4] + red[5] + red[6] + red[7];
  float inv = 1.f / s;
  u16x8 o;
  #pragma unroll
  for (int j = 0; j < 8; ++j) o[j] = f2bf(v[j] * inv);
  *((u16x8*)(sc + base + t * 8)) = o;
}

// x1 = LN(a_bf16 + b_bf16) * gamma + beta -> bf16 out. One block per 1024-wide row.
__global__ __launch_bounds__(256)
void add_ln_k(const u16* __restrict__ a, int lda, const u16* __restrict__ b,
              const float* __restrict__ gamma, const float* __restrict__ beta,
              u16* __restrict__ out)
{
  __shared__ float red[8];
  const long long row = blockIdx.x;
  const int t = threadIdx.x, wave = t >> 6, lane = t & 63;
  u16x4 av = *((const u16x4*)(a + row * lda + t * 4));
  u16x4 bv = *((const u16x4*)(b + row * 1024 + t * 4));
  float z[4] = { bf2f(av.x) + bf2f(bv.x), bf2f(av.y) + bf2f(bv.y),
                 bf2f(av.z) + bf2f(bv.z), bf2f(av.w) + bf2f(bv.w) };
  float s = z[0] + z[1] + z[2] + z[3];
  float ss = z[0]*z[0] + z[1]*z[1] + z[2]*z[2] + z[3]*z[3];
  #pragma unroll
  for (int off = 32; off > 0; off >>= 1) { s += __shfl_xor(s, off, 64); ss += __shfl_xor(ss, off, 64); }
  if (lane == 0) { red[wave] = s; red[4 + wave] = ss; }
  __syncthreads();
  s = red[0] + red[1] + red[2] + red[3];
  ss = red[4] + red[5] + red[6] + red[7];
  float mu = s * (1.f / 1024.f);
  float var = ss * (1.f / 1024.f) - mu * mu;
  float rstd = rsqrtf(var + 1e-5f);
  float4 g = ((const float4*)gamma)[t];
  float4 be = ((const float4*)beta)[t];
  u16x4 o;
  o.x = f2bf((z[0] - mu) * rstd * g.x + be.x);
  o.y = f2bf((z[1] - mu) * rstd * g.y + be.y);
  o.z = f2bf((z[2] - mu) * rstd * g.z + be.z);
  o.w = f2bf((z[3] - mu) * rstd * g.w + be.w);
  *((u16x4*)(out + row * 1024 + t * 4)) = o;
}

// out = relu(LN(a_bf16 + b_bf16) * gamma + beta) -> f32. One block per 1024-wide row.
__global__ __launch_bounds__(256)
void add_ln_relu_k(const u16* __restrict__ a, const u16* __restrict__ b,
                   const float* __restrict__ gamma, const float* __restrict__ beta,
                   float* __restrict__ out)
{
  __shared__ float red[8];
  const long long row = blockIdx.x;
  const int t = threadIdx.x, wave = t >> 6, lane = t & 63;
  u16x4 av = *((const u16x4*)(a + row * 1024 + t * 4));
  u16x4 bv = *((const u16x4*)(b + row * 1024 + t * 4));
  float z[4] = { bf2f(av.x) + bf2f(bv.x), bf2f(av.y) + bf2f(bv.y),
                 bf2f(av.z) + bf2f(bv.z), bf2f(av.w) + bf2f(bv.w) };
  float s = z[0] + z[1] + z[2] + z[3];
  float ss = z[0]*z[0] + z[1]*z[1] + z[2]*z[2] + z[3]*z[3];
  #pragma unroll
  for (int off = 32; off > 0; off >>= 1) { s += __shfl_xor(s, off, 64); ss += __shfl_xor(ss, off, 64); }
  if (lane == 0) { red[wave] = s; red[4 + wave] = ss; }
  __syncthreads();
  s = red[0] + red[1] + red[2] + red[3];
  ss = red[4] + red[5] + red[6] + red[7];
  float mu = s * (1.f / 1024.f);
  float var = ss * (1.f / 1024.f) - mu * mu;
  float rstd = rsqrtf(var + 1e-5f);
  float4 g = ((const float4*)gamma)[t];
  float4 be = ((const float4*)beta)[t];
  float4 o;
  o.x = fmaxf((z[0] - mu) * rstd * g.x + be.x, 0.f);
  o.y = fmaxf((z[1] - mu) * rstd * g.y + be.y, 0.f);
  o.z = fmaxf((z[2] - mu) * rstd * g.z + be.z, 0.f);
  o.w = fmaxf((z[3] - mu) * rstd * g.w + be.w, 0.f);
  ((float4*)(out + row * 1024))[t] = o;
}

extern "C" void kernel_launch(void* const* d_in, const int* in_sizes, int n_in,
                              void* d_out, int out_size, void* d_ws, size_t ws_size,
                              hipStream_t stream)
{
  const float* x    = (const float*)d_in[0];
  const float* wmlp = (const float*)d_in[1];
  const float* bmlp = (const float*)d_in[2];
  const float* wq   = (const float*)d_in[3];  const float* bq  = (const float*)d_in[4];
  const float* wk   = (const float*)d_in[5];  const float* bk  = (const float*)d_in[6];
  const float* wv   = (const float*)d_in[7];  const float* bv  = (const float*)d_in[8];
  const float* wm   = (const float*)d_in[9];  const float* bm  = (const float*)d_in[10];
  const float* g1   = (const float*)d_in[11]; const float* be1 = (const float*)d_in[12];
  const float* wf1  = (const float*)d_in[13]; const float* bf1 = (const float*)d_in[14];
  const float* wf2  = (const float*)d_in[15]; const float* bf2 = (const float*)d_in[16];
  const float* g2   = (const float*)d_in[17]; const float* be2 = (const float*)d_in[18];

  // B=4, S=2048, IN_C=768, HID=568 (MLP-N pad 768, QKVM-K pad 640), OUT_C=1024.
  char* ws = (char*)d_ws;
  size_t off = 0;
  auto alloc = [&](size_t bytes) { char* p = ws + off; off += (bytes + 255) & ~(size_t)255; return p; };
  u16*  W_MLP_T  = (u16*)alloc((size_t)768 * 768 * 2);
  u16*  W_QKVM_T = (u16*)alloc((size_t)4096 * 640 * 2);
  u16*  W_F1_T   = (u16*)alloc((size_t)1024 * 1024 * 2);
  u16*  W_F2_T   = (u16*)alloc((size_t)1024 * 1024 * 2);
  float* B_MLP   = (float*)alloc(768 * 4);
  float* B_QKVM  = (float*)alloc(4096 * 4);
  u16*  XBF      = (u16*)alloc((size_t)8192 * 768 * 2);
  u16*  H        = (u16*)alloc((size_t)8192 * 768 * 2);
  u16*  QKVM     = (u16*)alloc((size_t)8192 * 4096 * 2);
  u16*  VT       = (u16*)alloc((size_t)4 * 1024 * 2048 * 2);
  u16*  SC       = (u16*)alloc((size_t)4 * 2048 * 2048 * 2);
  u16*  AO       = (u16*)alloc((size_t)8192 * 1024 * 2);
  u16*  X1       = (u16*)alloc((size_t)8192 * 1024 * 2);
  u16*  T  = QKVM;                                          // ffn hidden bf16 [8192][1024]
  u16*  F  = QKVM + (size_t)8192 * 1024;                    // ffn out bf16 [8192][1024]

  hipFuncSetAttribute((const void*)gemm256v2<false, true, true >, hipFuncAttributeMaxDynamicSharedMemorySize, 131072);
  hipFuncSetAttribute((const void*)gemm256v2<false, true, false>, hipFuncAttributeMaxDynamicSharedMemorySize, 131072);
  hipFuncSetAttribute((const void*)gemm256n128<true,  true, true >, hipFuncAttributeMaxDynamicSharedMemorySize, 98304);
  hipFuncSetAttribute((const void*)gemm256n128<false, true, false>, hipFuncAttributeMaxDynamicSharedMemorySize, 98304);
  hipFuncSetAttribute((const void*)gemm256n128<false, true, true >, hipFuncAttributeMaxDynamicSharedMemorySize, 98304);

  dim3 tb(32, 8);

  // 1) cast x -> bf16
  cast_f32_bf16_k<<<(8192 * 768 / 4 + 255) / 256, 256, 0, stream>>>(x, XBF, 8192 * 768 / 4);
  // 2) weight transposes (fp32 [K][N] -> bf16 [Npad][Kpad])
  transpose_cast_pad<<<dim3(24, 24), tb, 0, stream>>>(wmlp, 768, 568, W_MLP_T, 768, 768);
  transpose_cast_pad<<<dim3(32, 20), tb, 0, stream>>>(wq, 568, 1024, W_QKVM_T + (size_t)0 * 1024 * 640, 1024, 640);
  transpose_cast_pad<<<dim3(32, 20), tb, 0, stream>>>(wk, 568, 1024, W_QKVM_T + (size_t)1 * 1024 * 640, 1024, 640);
  transpose_cast_pad<<<dim3(32, 20), tb, 0, stream>>>(wv, 568, 1024, W_QKVM_T + (size_t)2 * 1024 * 640, 1024, 640);
  transpose_cast_pad<<<dim3(32, 20), tb, 0, stream>>>(wm, 568, 1024, W_QKVM_T + (size_t)3 * 1024 * 640, 1024, 640);
  transpose_cast_pad<<<dim3(32, 32), tb, 0, stream>>>(wf1, 1024, 1024, W_F1_T, 1024, 1024);
  transpose_cast_pad<<<dim3(32, 32), tb, 0, stream>>>(wf2, 1024, 1024, W_F2_T, 1024, 1024);
  prep_bias_k<<<16, 256, 0, stream>>>(bmlp, bq, bk, bv, bm, B_MLP, B_QKVM);

  // 3) h = relu(x @ w_mlp + b)   M=8192 N=768 K=768  (n128, grid 6x32=192)
  gemm256n128<true, true, true><<<dim3(6, 32, 1), 512, 98304, stream>>>(
      XBF, 0, 768, W_MLP_T, 0, 768, B_MLP, H, 0, 768, 768, 1.0f);
  // 4) qkvm = h @ [wq|wk|wv|wm] + b   M=8192 N=4096 K=640  (v2, grid 16x32=512)
  gemm256v2<false, true, true><<<dim3(16, 32, 1), 512, 131072, stream>>>(
      H, 0, 768, W_QKVM_T, 0, 640, B_QKVM, QKVM, 0, 4096, 640, 1.0f);
  // 5) v^T per batch: [2048][1024] (ld 4096) -> [1024][2048]  (transpose64, grid 16x32x4)
  transpose64_k<<<dim3(16, 32, 4), 256, 0, stream>>>(
      QKVM + 2048, (long long)2048 * 4096, 4096, VT, (long long)1024 * 2048, 2048);
  // 6) scores = q @ k^T * 1/32   per batch M=N=2048 K=1024  (v2, grid 8x8x4=256)
  gemm256v2<false, true, false><<<dim3(8, 8, 4), 512, 131072, stream>>>(
      QKVM, (long long)2048 * 4096, 4096, QKVM + 1024, (long long)2048 * 4096, 4096,
      nullptr, SC, (long long)2048 * 2048, 2048, 1024, 0.03125f);
  // 7) P = softmax(scores) in-place
  softmax_rows_k<<<8192, 256, 0, stream>>>(SC);
  // 8) attn_out = P @ v   per batch M=2048 N=1024 K=2048  (n128, grid 8x8x4=256)
  gemm256n128<false, true, false><<<dim3(8, 8, 4), 512, 98304, stream>>>(
      SC, (long long)2048 * 2048, 2048, VT, (long long)1024 * 2048, 2048,
      nullptr, AO, (long long)2048 * 1024, 1024, 2048, 1.0f);
  // 9) x1 = LN(m + attn_out)
  add_ln_k<<<8192, 256, 0, stream>>>(QKVM + 3072, 4096, AO, g1, be1, X1);
  // 10) t = relu(x1 @ wf1 + bf1)   (n128, grid 8x32=256)
  gemm256n128<true, true, true><<<dim3(8, 32, 1), 512, 98304, stream>>>(
      X1, 0, 1024, W_F1_T, 0, 1024, bf1, T, 0, 1024, 1024, 1.0f);
  // 11) f = t @ wf2 + bf2 (bf16)   (n128, grid 8x32=256)
  gemm256n128<false, true, true><<<dim3(8, 32, 1), 512, 98304, stream>>>(
      T, 0, 1024, W_F2_T, 0, 1024, bf2, F, 0, 1024, 1024, 1.0f);
  // 12) out = relu(LN(x1 + f))
  add_ln_relu_k<<<8192, 256, 0, stream>>>(X1, F, g2, be2, (float*)d_out);
}

// Round 10
// 240.528 us; speedup vs baseline: 1.1428x; 1.0536x over previous
//
#include <hip/hip_runtime.h>

#define DI __device__ __forceinline__

typedef unsigned short u16;
typedef __attribute__((__ext_vector_type__(8))) __bf16 bf16x8;
typedef __attribute__((__ext_vector_type__(4))) float f32x4;
typedef __attribute__((__ext_vector_type__(4))) unsigned short u16x4;
typedef __attribute__((__ext_vector_type__(8))) unsigned short u16x8;

DI float bf2f(u16 u) { union { unsigned int i; float f; } x; x.i = ((unsigned int)u) << 16; return x.f; }
DI u16 f2bf(float f) {
  union { float f; unsigned int i; } x; x.f = f;
  unsigned int r = x.i + 0x7fffu + ((x.i >> 16) & 1u);
  return (u16)(r >> 16);
}

// async global->LDS, 16B per lane; LDS dest = wave-uniform base + lane*16
DI void gload_lds16(const void* g, void* lds) {
  __builtin_amdgcn_global_load_lds((const __attribute__((address_space(1))) unsigned int*)g,
                                   (__attribute__((address_space(3))) unsigned int*)lds, 16, 0, 0);
}

#define MFMA16(a, b, c) __builtin_amdgcn_mfma_f32_16x16x32_bf16((a), (b), (c), 0, 0, 0)

// =====================================================================================
// gemm256v2: C[M,N] = A[M,K] @ Bt[N,K]^T * scale + bias   (proven best: ~858 TF)
// BM=BN=256, BK=64. 8 waves (2M x 4N), wave tile 128x64 (acc[8][4]).
// LDS: 2 buffers x 64KB = 128KB dynamic. Counted vmcnt(2)/vmcnt(8), never cold drain.
// k-granule XOR LDS layout; linear gload_lds dest, pre-permuted GLOBAL source (rule 21).
// Epilogue XOR-swizzled LDS staging -> coalesced 16B stores.
// Requires M%256==0, N%256==0, K%64==0. grid (N/256, M/256, z); (gx*gy)%8==0.
// =====================================================================================
template<bool RELU, bool OUT_BF16, bool HAS_BIAS>
__global__ __launch_bounds__(512, 2)
void gemm256v2(const u16* __restrict__ A, long long sAb, int lda,
               const u16* __restrict__ Bt, long long sBb, int ldb,
               const float* __restrict__ bias,
               void* __restrict__ C, long long sCb, int ldc,
               int K, float scale)
{
  extern __shared__ __align__(16) u16 lds[];

  const int tid = threadIdx.x;
  const int w = tid >> 6, l = tid & 63;
  const int wm = w >> 2, wn = w & 3;

  const int gx = gridDim.x;
  const int nwg = gx * gridDim.y;
  const int f = blockIdx.x + gx * blockIdx.y;
  const int fs = (f & 7) * (nwg >> 3) + (f >> 3);
  const int bx = fs % gx, by = fs / gx;

  const long long bm = (long long)by * 256;
  const long long bn = (long long)bx * 256;
  const u16* Ab = A + (long long)blockIdx.z * sAb;
  const u16* Btb = Bt + (long long)blockIdx.z * sBb;

  const int trow = tid >> 3;
  const int tg = (tid & 7) ^ (trow & 7);
  const u16* sA = Ab + (bm + trow) * (long long)lda + tg * 8;
  const u16* sB = Btb + (bn + trow) * (long long)ldb + tg * 8;
  const long long la64 = (long long)64 * lda, lb64 = (long long)64 * ldb;

  const int swz0 = (((l >> 4) ^ (l & 7))) * 8;
  const int aB = (wm * 128 + (l & 15)) * 64;
  const int bB = 16384 + (wn * 64 + (l & 15)) * 64;

  f32x4 acc[8][4] = {};
  const int NKT = K >> 6;

  {
    u16* sp = lds;
    gload_lds16(sA, sp + w * 512);
    gload_lds16(sA + 2 * la64, sp + 8192 + w * 512);
    gload_lds16(sB, sp + 16384 + w * 512);
    gload_lds16(sB + lb64, sp + 20480 + w * 512);
    gload_lds16(sB + 2 * lb64, sp + 24576 + w * 512);
    gload_lds16(sB + 3 * lb64, sp + 28672 + w * 512);
    gload_lds16(sA + la64, sp + 4096 + w * 512);
    gload_lds16(sA + 3 * la64, sp + 12288 + w * 512);
  }

  for (int kt = 0; kt < NKT; ++kt) {
    const u16* bp = lds + (kt & 1) * 32768;
    u16* sp = lds + ((kt & 1) ^ 1) * 32768;
    const bool st = (kt + 1) < NKT;
    const long long ko = (long long)(kt + 1) * 64;

    asm volatile("s_waitcnt vmcnt(2)" ::: "memory");
    __builtin_amdgcn_s_barrier();

    if (st) {
      gload_lds16(sA + ko, sp + w * 512);
      gload_lds16(sA + 2 * la64 + ko, sp + 8192 + w * 512);
      gload_lds16(sB + ko, sp + 16384 + w * 512);
      gload_lds16(sB + lb64 + ko, sp + 20480 + w * 512);
      gload_lds16(sB + 2 * lb64 + ko, sp + 24576 + w * 512);
      gload_lds16(sB + 3 * lb64 + ko, sp + 28672 + w * 512);
    }

    bf16x8 bF[4][2], aF[4][2];
    #pragma unroll
    for (int nf = 0; nf < 4; ++nf) {
      bF[nf][0] = *(const bf16x8*)(bp + bB + nf * 1024 + swz0);
      bF[nf][1] = *(const bf16x8*)(bp + bB + nf * 1024 + (swz0 ^ 32));
    }
    #pragma unroll
    for (int mf = 0; mf < 4; ++mf) {
      aF[mf][0] = *(const bf16x8*)(bp + aB + mf * 1024 + swz0);
      aF[mf][1] = *(const bf16x8*)(bp + aB + mf * 1024 + (swz0 ^ 32));
    }
    if (st) {
      gload_lds16(sA + la64 + ko, sp + 4096 + w * 512);
      gload_lds16(sA + 3 * la64 + ko, sp + 12288 + w * 512);
    }
    __builtin_amdgcn_s_setprio(1);
    #pragma unroll
    for (int mf = 0; mf < 4; ++mf)
      #pragma unroll
      for (int nf = 0; nf < 4; ++nf) {
        acc[mf][nf] = MFMA16(aF[mf][0], bF[nf][0], acc[mf][nf]);
        acc[mf][nf] = MFMA16(aF[mf][1], bF[nf][1], acc[mf][nf]);
      }
    __builtin_amdgcn_s_setprio(0);

    if (st) asm volatile("s_waitcnt vmcnt(8)" ::: "memory");
    else    asm volatile("s_waitcnt vmcnt(0)" ::: "memory");
    __builtin_amdgcn_s_barrier();

    #pragma unroll
    for (int mf = 0; mf < 4; ++mf) {
      aF[mf][0] = *(const bf16x8*)(bp + aB + (mf + 4) * 1024 + swz0);
      aF[mf][1] = *(const bf16x8*)(bp + aB + (mf + 4) * 1024 + (swz0 ^ 32));
    }
    __builtin_amdgcn_s_setprio(1);
    #pragma unroll
    for (int mf = 0; mf < 4; ++mf)
      #pragma unroll
      for (int nf = 0; nf < 4; ++nf) {
        acc[mf + 4][nf] = MFMA16(aF[mf][0], bF[nf][0], acc[mf + 4][nf]);
        acc[mf + 4][nf] = MFMA16(aF[mf][1], bF[nf][1], acc[mf + 4][nf]);
      }
    __builtin_amdgcn_s_setprio(0);
  }

  __syncthreads();
  float bias4[4];
  if (HAS_BIAS) {
    #pragma unroll
    for (int nf = 0; nf < 4; ++nf) bias4[nf] = bias[bn + wn * 64 + (l & 15) + nf * 16];
  }
  float* fl = (float*)lds + w * 1024;
  const long long cbase = (long long)blockIdx.z * sCb;
  const int q = l >> 4;
  #pragma unroll
  for (int mf = 0; mf < 8; ++mf) {
    #pragma unroll
    for (int nf = 0; nf < 4; ++nf) {
      #pragma unroll
      for (int r = 0; r < 4; ++r) {
        float v = acc[mf][nf][r] * scale;
        if (HAS_BIAS) v += bias4[nf];
        if (RELU) v = fmaxf(v, 0.f);
        fl[(q * 4 + r) * 64 + ((((l & 15) + nf * 16)) ^ (q << 4))] = v;
      }
    }
    asm volatile("s_waitcnt lgkmcnt(0)" ::: "memory");
    #pragma unroll
    for (int p = 0; p < 4; ++p) {
      f32x4 v = *(const f32x4*)(fl + (p * 4 + q) * 64 + (((l & 15) * 4) ^ (p << 4)));
      const long long row = bm + wm * 128 + mf * 16 + p * 4 + q;
      const long long cidx = cbase + row * ldc + bn + wn * 64 + (l & 15) * 4;
      if (OUT_BF16) {
        u16x4 o; o.x = f2bf(v.x); o.y = f2bf(v.y); o.z = f2bf(v.z); o.w = f2bf(v.w);
        *(u16x4*)((u16*)C + cidx) = o;
      } else {
        *(f32x4*)((float*)C + cidx) = v;
      }
    }
    asm volatile("s_waitcnt lgkmcnt(0)" ::: "memory");
  }
}

// =====================================================================================
// gemm256n128: v2 template with BN=128 (full-grid fill for N<=1024-class GEMMs).
// BM=256, BN=128, BK=64. 8 waves (2M x 4N), wave tile 128x32 (acc[8][2]).
// LDS: 2 buffers x 48KB = 96KB dynamic. Counted vmcnt(2)/vmcnt(6).
// Requires M%256==0, N%128==0, K%64==0. grid (N/128, M/256, z); (gx*gy)%8==0.
// =====================================================================================
template<bool RELU, bool OUT_BF16, bool HAS_BIAS>
__global__ __launch_bounds__(512, 2)
void gemm256n128(const u16* __restrict__ A, long long sAb, int lda,
                 const u16* __restrict__ Bt, long long sBb, int ldb,
                 const float* __restrict__ bias,
                 void* __restrict__ C, long long sCb, int ldc,
                 int K, float scale)
{
  extern __shared__ __align__(16) u16 lds[];

  const int tid = threadIdx.x;
  const int w = tid >> 6, l = tid & 63;
  const int wm = w >> 2, wn = w & 3;

  const int gx = gridDim.x;
  const int nwg = gx * gridDim.y;
  const int f = blockIdx.x + gx * blockIdx.y;
  const int fs = (f & 7) * (nwg >> 3) + (f >> 3);
  const int bx = fs % gx, by = fs / gx;

  const long long bm = (long long)by * 256;
  const long long bn = (long long)bx * 128;
  const u16* Ab = A + (long long)blockIdx.z * sAb;
  const u16* Btb = Bt + (long long)blockIdx.z * sBb;

  const int trow = tid >> 3;
  const int tg = (tid & 7) ^ (trow & 7);
  const u16* gA = Ab + (bm + trow) * (long long)lda + tg * 8;
  const u16* gB = Btb + (bn + trow) * (long long)ldb + tg * 8;
  const long long la64 = (long long)64 * lda, lb64 = (long long)64 * ldb;

  const int swz0 = ((l >> 4) ^ (l & 7)) * 8;
  const int aB = (wm * 128 + (l & 15)) * 64;          // A region: [0, 16384) u16
  const int bB = 16384 + (wn * 32 + (l & 15)) * 64;   // B region: [16384, 24576) u16

  f32x4 acc[8][2] = {};
  const int NKT = K >> 6;

  gload_lds16(gA,            lds + w * 512);
  gload_lds16(gA + 2 * la64, lds + 8192 + w * 512);
  gload_lds16(gB,            lds + 16384 + w * 512);
  gload_lds16(gB + lb64,     lds + 20480 + w * 512);
  gload_lds16(gA + la64,     lds + 4096 + w * 512);
  gload_lds16(gA + 3 * la64, lds + 12288 + w * 512);

  for (int kt = 0; kt < NKT; ++kt) {
    const u16* bp = lds + (kt & 1) * 24576;
    u16* sp = lds + ((kt & 1) ^ 1) * 24576;
    const bool st = (kt + 1) < NKT;
    const long long ko = (long long)(kt + 1) * 64;

    asm volatile("s_waitcnt vmcnt(2)" ::: "memory");
    __builtin_amdgcn_s_barrier();

    if (st) {
      gload_lds16(gA + ko,            sp + w * 512);
      gload_lds16(gA + 2 * la64 + ko, sp + 8192 + w * 512);
      gload_lds16(gB + ko,            sp + 16384 + w * 512);
      gload_lds16(gB + lb64 + ko,     sp + 20480 + w * 512);
    }

    bf16x8 bF[2][2], aF[4][2];
    #pragma unroll
    for (int nf = 0; nf < 2; ++nf) {
      bF[nf][0] = *(const bf16x8*)(bp + bB + nf * 1024 + swz0);
      bF[nf][1] = *(const bf16x8*)(bp + bB + nf * 1024 + (swz0 ^ 32));
    }
    #pragma unroll
    for (int mf = 0; mf < 4; ++mf) {
      aF[mf][0] = *(const bf16x8*)(bp + aB + mf * 1024 + swz0);
      aF[mf][1] = *(const bf16x8*)(bp + aB + mf * 1024 + (swz0 ^ 32));
    }
    if (st) {
      gload_lds16(gA + la64 + ko,     sp + 4096 + w * 512);
      gload_lds16(gA + 3 * la64 + ko, sp + 12288 + w * 512);
    }
    __builtin_amdgcn_s_setprio(1);
    #pragma unroll
    for (int mf = 0; mf < 4; ++mf)
      #pragma unroll
      for (int nf = 0; nf < 2; ++nf) {
        acc[mf][nf] = MFMA16(aF[mf][0], bF[nf][0], acc[mf][nf]);
        acc[mf][nf] = MFMA16(aF[mf][1], bF[nf][1], acc[mf][nf]);
      }
    __builtin_amdgcn_s_setprio(0);

    if (st) asm volatile("s_waitcnt vmcnt(6)" ::: "memory");
    else    asm volatile("s_waitcnt vmcnt(0)" ::: "memory");
    __builtin_amdgcn_s_barrier();

    #pragma unroll
    for (int mf = 0; mf < 4; ++mf) {
      aF[mf][0] = *(const bf16x8*)(bp + aB + (mf + 4) * 1024 + swz0);
      aF[mf][1] = *(const bf16x8*)(bp + aB + (mf + 4) * 1024 + (swz0 ^ 32));
    }
    __builtin_amdgcn_s_setprio(1);
    #pragma unroll
    for (int mf = 0; mf < 4; ++mf)
      #pragma unroll
      for (int nf = 0; nf < 2; ++nf) {
        acc[mf + 4][nf] = MFMA16(aF[mf][0], bF[nf][0], acc[mf + 4][nf]);
        acc[mf + 4][nf] = MFMA16(aF[mf][1], bF[nf][1], acc[mf + 4][nf]);
      }
    __builtin_amdgcn_s_setprio(0);
  }

  __syncthreads();
  float bias2[2];
  if (HAS_BIAS) {
    #pragma unroll
    for (int nf = 0; nf < 2; ++nf) bias2[nf] = bias[bn + wn * 32 + (l & 15) + nf * 16];
  }
  float* fl = (float*)lds + w * 512;
  const long long cbase = (long long)blockIdx.z * sCb;
  const int q = l >> 4;
  #pragma unroll
  for (int mf = 0; mf < 8; ++mf) {
    #pragma unroll
    for (int nf = 0; nf < 2; ++nf) {
      #pragma unroll
      for (int r = 0; r < 4; ++r) {
        float v = acc[mf][nf][r] * scale;
        if (HAS_BIAS) v += bias2[nf];
        if (RELU) v = fmaxf(v, 0.f);
        fl[(q * 4 + r) * 32 + ((((l & 15) + nf * 16)) ^ ((q & 1) << 4))] = v;
      }
    }
    asm volatile("s_waitcnt lgkmcnt(0)" ::: "memory");
    #pragma unroll
    for (int p = 0; p < 2; ++p) {
      const int orow = p * 8 + (l >> 3);
      const int X = ((orow >> 2) & 1) << 4;
      f32x4 v = *(const f32x4*)(fl + orow * 32 + (((l & 7) * 4) ^ X));
      const long long row = bm + wm * 128 + mf * 16 + orow;
      const long long cidx = cbase + row * ldc + bn + wn * 32 + (l & 7) * 4;
      if (OUT_BF16) {
        u16x4 o; o.x = f2bf(v.x); o.y = f2bf(v.y); o.z = f2bf(v.z); o.w = f2bf(v.w);
        *(u16x4*)((u16*)C + cidx) = o;
      } else {
        *(f32x4*)((float*)C + cidx) = v;
      }
    }
    asm volatile("s_waitcnt lgkmcnt(0)" ::: "memory");
  }
}

// ---------------- transpose fp32 [inR][inC] -> bf16 [outR][outC], zero-padded ----------------
__global__ void transpose_cast_pad(const float* __restrict__ in, int inR, int inC,
                                   u16* __restrict__ out, int outR, int outC)
{
  __shared__ float tile[32][33];
  const int c0 = blockIdx.x * 32;
  const int r0 = blockIdx.y * 32;
  const int tx = threadIdx.x, ty = threadIdx.y;
  for (int i = ty; i < 32; i += 8) {
    int r = r0 + i, c = c0 + tx;
    tile[i][tx] = (r < inR && c < inC) ? in[(long long)r * inC + c] : 0.f;
  }
  __syncthreads();
  for (int i = ty; i < 32; i += 8) {
    int orow = c0 + i, ocol = r0 + tx;
    if (orow < outR && ocol < outC)
      out[(long long)orow * outC + ocol] = f2bf(tile[tx][i]);
  }
}

// z-batched variant: blockIdx.z selects source; outputs at out + z*sOut.
__global__ void transpose_cast_pad4(const float* __restrict__ p0, const float* __restrict__ p1,
                                    const float* __restrict__ p2, const float* __restrict__ p3,
                                    int inR, int inC,
                                    u16* __restrict__ out, long long sOut, int outR, int outC)
{
  __shared__ float tile[32][33];
  const float* in = (blockIdx.z == 0) ? p0 : (blockIdx.z == 1) ? p1 : (blockIdx.z == 2) ? p2 : p3;
  u16* o = out + (long long)blockIdx.z * sOut;
  const int c0 = blockIdx.x * 32;
  const int r0 = blockIdx.y * 32;
  const int tx = threadIdx.x, ty = threadIdx.y;
  for (int i = ty; i < 32; i += 8) {
    int r = r0 + i, c = c0 + tx;
    tile[i][tx] = (r < inR && c < inC) ? in[(long long)r * inC + c] : 0.f;
  }
  __syncthreads();
  for (int i = ty; i < 32; i += 8) {
    int orow = c0 + i, ocol = r0 + tx;
    if (orow < outR && ocol < outC)
      o[(long long)orow * outC + ocol] = f2bf(tile[tx][i]);
  }
}

// ---------------- transpose64: bf16 [R][C] (ld ldi) -> [C][R] (ld ldo), batched ----------------
__global__ __launch_bounds__(256)
void transpose64_k(const u16* __restrict__ in, long long sIb, int ldi,
                   u16* __restrict__ out, long long sOb, int ldo)
{
  __shared__ u16 tile[64][72];
  const u16* inp = in + (long long)blockIdx.z * sIb;
  u16* outp = out + (long long)blockIdx.z * sOb;
  const int r0 = blockIdx.y * 64, c0 = blockIdx.x * 64;
  const int t = threadIdx.x;
  const int jr = t >> 3, ch = t & 7;
  #pragma unroll
  for (int it = 0; it < 2; ++it) {
    const int row = jr + it * 32;
    u16x8 v = *(const u16x8*)(inp + (long long)(r0 + row) * ldi + c0 + ch * 8);
    *(u16x8*)(&tile[row][ch * 8]) = v;
  }
  __syncthreads();
  #pragma unroll
  for (int it = 0; it < 2; ++it) {
    const int orow = jr + it * 32;
    u16x8 v;
    #pragma unroll
    for (int e = 0; e < 8; ++e) v[e] = tile[ch * 8 + e][orow];
    *(u16x8*)(outp + (long long)(c0 + orow) * ldo + r0 + ch * 8) = v;
  }
}

__global__ void cast_f32_bf16_k(const float* __restrict__ in, u16* __restrict__ out, int n4)
{
  int i = blockIdx.x * blockDim.x + threadIdx.x;
  if (i >= n4) return;
  float4 v = ((const float4*)in)[i];
  u16x4 o; o.x = f2bf(v.x); o.y = f2bf(v.y); o.z = f2bf(v.z); o.w = f2bf(v.w);
  ((u16x4*)out)[i] = o;
}

__global__ void prep_bias_k(const float* __restrict__ bmlp, const float* __restrict__ bq,
                            const float* __restrict__ bk, const float* __restrict__ bv,
                            const float* __restrict__ bm,
                            float* __restrict__ outMlp, float* __restrict__ outQkvm)
{
  int i = blockIdx.x * 256 + threadIdx.x;
  if (i < 640) outMlp[i] = (i < 568) ? bmlp[i] : 0.f;
  if (i < 4096) {
    const float* s = (i < 1024) ? bq : (i < 2048) ? bk : (i < 3072) ? bv : bm;
    outQkvm[i] = s[i & 1023];
  }
}

// in-place row softmax over 2048 bf16 elements; one block per row
__global__ __launch_bounds__(256)
void softmax_rows_k(u16* __restrict__ sc)
{
  __shared__ float red[8];
  const long long base = (long long)blockIdx.x * 2048;
  const int t = threadIdx.x, wave = t >> 6, lane = t & 63;
  u16x8 v8 = *((const u16x8*)(sc + base + t * 8));
  float v[8];
  #pragma unroll
  for (int j = 0; j < 8; ++j) v[j] = bf2f(v8[j]);
  float m = v[0];
  #pragma unroll
  for (int j = 1; j < 8; ++j) m = fmaxf(m, v[j]);
  #pragma unroll
  for (int off = 32; off > 0; off >>= 1) m = fmaxf(m, __shfl_xor(m, off, 64));
  if (lane == 0) red[wave] = m;
  __syncthreads();
  m = fmaxf(fmaxf(red[0], red[1]), fmaxf(red[2], red[3]));
  float s = 0.f;
  #pragma unroll
  for (int j = 0; j < 8; ++j) { v[j] = __expf(v[j] - m); s += v[j]; }
  #pragma unroll
  for (int off = 32; off > 0; off >>= 1) s += __shfl_xor(s, off, 64);
  if (lane == 0) red[4 + wave] = s;
  __syncthreads();
  s = red[4] + red[5] + red[6] + red[7];
  float inv = 1.f / s;
  u16x8 o;
  #pragma unroll
  for (int j = 0; j < 8; ++j) o[j] = f2bf(v[j] * inv);
  *((u16x8*)(sc + base + t * 8)) = o;
}

// x1 = LN(a_bf16 + b_bf16) * gamma + beta -> bf16 out. One block per 1024-wide row.
__global__ __launch_bounds__(256)
void add_ln_k(const u16* __restrict__ a, int lda, const u16* __restrict__ b,
              const float* __restrict__ gamma, const float* __restrict__ beta,
              u16* __restrict__ out)
{
  __shared__ float red[8];
  const long long row = blockIdx.x;
  const int t = threadIdx.x, wave = t >> 6, lane = t & 63;
  u16x4 av = *((const u16x4*)(a + row * lda + t * 4));
  u16x4 bv = *((const u16x4*)(b + row * 1024 + t * 4));
  float z[4] = { bf2f(av.x) + bf2f(bv.x), bf2f(av.y) + bf2f(bv.y),
                 bf2f(av.z) + bf2f(bv.z), bf2f(av.w) + bf2f(bv.w) };
  float s = z[0] + z[1] + z[2] + z[3];
  float ss = z[0]*z[0] + z[1]*z[1] + z[2]*z[2] + z[3]*z[3];
  #pragma unroll
  for (int off = 32; off > 0; off >>= 1) { s += __shfl_xor(s, off, 64); ss += __shfl_xor(ss, off, 64); }
  if (lane == 0) { red[wave] = s; red[4 + wave] = ss; }
  __syncthreads();
  s = red[0] + red[1] + red[2] + red[3];
  ss = red[4] + red[5] + red[6] + red[7];
  float mu = s * (1.f / 1024.f);
  float var = ss * (1.f / 1024.f) - mu * mu;
  float rstd = rsqrtf(var + 1e-5f);
  float4 g = ((const float4*)gamma)[t];
  float4 be = ((const float4*)beta)[t];
  u16x4 o;
  o.x = f2bf((z[0] - mu) * rstd * g.x + be.x);
  o.y = f2bf((z[1] - mu) * rstd * g.y + be.y);
  o.z = f2bf((z[2] - mu) * rstd * g.z + be.z);
  o.w = f2bf((z[3] - mu) * rstd * g.w + be.w);
  *((u16x4*)(out + row * 1024 + t * 4)) = o;
}

// out = relu(LN(a_bf16 + b_bf16) * gamma + beta) -> f32. One block per 1024-wide row.
__global__ __launch_bounds__(256)
void add_ln_relu_k(const u16* __restrict__ a, const u16* __restrict__ b,
                   const float* __restrict__ gamma, const float* __restrict__ beta,
                   float* __restrict__ out)
{
  __shared__ float red[8];
  const long long row = blockIdx.x;
  const int t = threadIdx.x, wave = t >> 6, lane = t & 63;
  u16x4 av = *((const u16x4*)(a + row * 1024 + t * 4));
  u16x4 bv = *((const u16x4*)(b + row * 1024 + t * 4));
  float z[4] = { bf2f(av.x) + bf2f(bv.x), bf2f(av.y) + bf2f(bv.y),
                 bf2f(av.z) + bf2f(bv.z), bf2f(av.w) + bf2f(bv.w) };
  float s = z[0] + z[1] + z[2] + z[3];
  float ss = z[0]*z[0] + z[1]*z[1] + z[2]*z[2] + z[3]*z[3];
  #pragma unroll
  for (int off = 32; off > 0; off >>= 1) { s += __shfl_xor(s, off, 64); ss += __shfl_xor(ss, off, 64); }
  if (lane == 0) { red[wave] = s; red[4 + wave] = ss; }
  __syncthreads();
  s = red[0] + red[1] + red[2] + red[3];
  ss = red[4] + red[5] + red[6] + red[7];
  float mu = s * (1.f / 1024.f);
  float var = ss * (1.f / 1024.f) - mu * mu;
  float rstd = rsqrtf(var + 1e-5f);
  float4 g = ((const float4*)gamma)[t];
  float4 be = ((const float4*)beta)[t];
  float4 o;
  o.x = fmaxf((z[0] - mu) * rstd * g.x + be.x, 0.f);
  o.y = fmaxf((z[1] - mu) * rstd * g.y + be.y, 0.f);
  o.z = fmaxf((z[2] - mu) * rstd * g.z + be.z, 0.f);
  o.w = fmaxf((z[3] - mu) * rstd * g.w + be.w, 0.f);
  ((float4*)(out + row * 1024))[t] = o;
}

extern "C" void kernel_launch(void* const* d_in, const int* in_sizes, int n_in,
                              void* d_out, int out_size, void* d_ws, size_t ws_size,
                              hipStream_t stream)
{
  const float* x    = (const float*)d_in[0];
  const float* wmlp = (const float*)d_in[1];
  const float* bmlp = (const float*)d_in[2];
  const float* wq   = (const float*)d_in[3];  const float* bq  = (const float*)d_in[4];
  const float* wk   = (const float*)d_in[5];  const float* bk  = (const float*)d_in[6];
  const float* wv   = (const float*)d_in[7];  const float* bv  = (const float*)d_in[8];
  const float* wm   = (const float*)d_in[9];  const float* bm  = (const float*)d_in[10];
  const float* g1   = (const float*)d_in[11]; const float* be1 = (const float*)d_in[12];
  const float* wf1  = (const float*)d_in[13]; const float* bf1 = (const float*)d_in[14];
  const float* wf2  = (const float*)d_in[15]; const float* bf2 = (const float*)d_in[16];
  const float* g2   = (const float*)d_in[17]; const float* be2 = (const float*)d_in[18];

  // B=4, S=2048, IN_C=768, HID=568 (padded to 640 everywhere), OUT_C=1024.
  char* ws = (char*)d_ws;
  size_t off = 0;
  auto alloc = [&](size_t bytes) { char* p = ws + off; off += (bytes + 255) & ~(size_t)255; return p; };
  u16*  W_MLP_T  = (u16*)alloc((size_t)640 * 768 * 2);     // [640][768]
  u16*  W_QKVM_T = (u16*)alloc((size_t)4096 * 640 * 2);    // [4096][640]
  u16*  W_F1_T   = (u16*)alloc((size_t)1024 * 1024 * 2);   // contiguous with W_F2_T
  u16*  W_F2_T   = (u16*)alloc((size_t)1024 * 1024 * 2);
  float* B_MLP   = (float*)alloc(640 * 4);
  float* B_QKVM  = (float*)alloc(4096 * 4);
  u16*  XBF      = (u16*)alloc((size_t)8192 * 768 * 2);
  u16*  H        = (u16*)alloc((size_t)8192 * 640 * 2);    // relu(mlp), cols 568..639 = 0
  u16*  QKVM     = (u16*)alloc((size_t)8192 * 4096 * 2);   // q|k|v|m, ld 4096
  u16*  VT       = (u16*)alloc((size_t)4 * 1024 * 2048 * 2);
  u16*  SC       = (u16*)alloc((size_t)4 * 2048 * 2048 * 2);
  u16*  AO       = (u16*)alloc((size_t)8192 * 1024 * 2);
  u16*  X1       = (u16*)alloc((size_t)8192 * 1024 * 2);
  u16*  T  = QKVM;                                          // ffn hidden bf16 [8192][1024]
  u16*  F  = QKVM + (size_t)8192 * 1024;                    // ffn out bf16 [8192][1024]

  hipFuncSetAttribute((const void*)gemm256v2<false, true, true >, hipFuncAttributeMaxDynamicSharedMemorySize, 131072);
  hipFuncSetAttribute((const void*)gemm256v2<false, true, false>, hipFuncAttributeMaxDynamicSharedMemorySize, 131072);
  hipFuncSetAttribute((const void*)gemm256n128<true,  true, true >, hipFuncAttributeMaxDynamicSharedMemorySize, 98304);
  hipFuncSetAttribute((const void*)gemm256n128<false, true, false>, hipFuncAttributeMaxDynamicSharedMemorySize, 98304);
  hipFuncSetAttribute((const void*)gemm256n128<false, true, true >, hipFuncAttributeMaxDynamicSharedMemorySize, 98304);

  dim3 tb(32, 8);

  // 1) cast x -> bf16
  cast_f32_bf16_k<<<(8192 * 768 / 4 + 255) / 256, 256, 0, stream>>>(x, XBF, 8192 * 768 / 4);
  // 2) weight transposes (fp32 [K][N] -> bf16 [Npad][Kpad]) -- batched
  transpose_cast_pad<<<dim3(20, 24), tb, 0, stream>>>(wmlp, 768, 568, W_MLP_T, 640, 768);
  transpose_cast_pad4<<<dim3(32, 20, 4), tb, 0, stream>>>(
      wq, wk, wv, wm, 568, 1024, W_QKVM_T, (long long)1024 * 640, 1024, 640);
  transpose_cast_pad4<<<dim3(32, 32, 2), tb, 0, stream>>>(
      wf1, wf2, wf1, wf2, 1024, 1024, W_F1_T, (long long)1024 * 1024, 1024, 1024);
  prep_bias_k<<<16, 256, 0, stream>>>(bmlp, bq, bk, bv, bm, B_MLP, B_QKVM);

  // 3) h = relu(x @ w_mlp + b)   M=8192 N=640 K=768  (n128, grid 5x32=160)
  gemm256n128<true, true, true><<<dim3(5, 32, 1), 512, 98304, stream>>>(
      XBF, 0, 768, W_MLP_T, 0, 768, B_MLP, H, 0, 640, 768, 1.0f);
  // 4) qkvm = h @ [wq|wk|wv|wm] + b   M=8192 N=4096 K=640  (v2, grid 16x32=512)
  gemm256v2<false, true, true><<<dim3(16, 32, 1), 512, 131072, stream>>>(
      H, 0, 640, W_QKVM_T, 0, 640, B_QKVM, QKVM, 0, 4096, 640, 1.0f);
  // 5) v^T per batch: [2048][1024] (ld 4096) -> [1024][2048]
  transpose64_k<<<dim3(16, 32, 4), 256, 0, stream>>>(
      QKVM + 2048, (long long)2048 * 4096, 4096, VT, (long long)1024 * 2048, 2048);
  // 6) scores = q @ k^T * 1/32   per batch M=N=2048 K=1024  (v2, grid 8x8x4=256)
  gemm256v2<false, true, false><<<dim3(8, 8, 4), 512, 131072, stream>>>(
      QKVM, (long long)2048 * 4096, 4096, QKVM + 1024, (long long)2048 * 4096, 4096,
      nullptr, SC, (long long)2048 * 2048, 2048, 1024, 0.03125f);
  // 7) P = softmax(scores) in-place
  softmax_rows_k<<<8192, 256, 0, stream>>>(SC);
  // 8) attn_out = P @ v   per batch M=2048 N=1024 K=2048  (n128, grid 8x8x4=256)
  gemm256n128<false, true, false><<<dim3(8, 8, 4), 512, 98304, stream>>>(
      SC, (long long)2048 * 2048, 2048, VT, (long long)1024 * 2048, 2048,
      nullptr, AO, (long long)2048 * 1024, 1024, 2048, 1.0f);
  // 9) x1 = LN(m + attn_out)
  add_ln_k<<<8192, 256, 0, stream>>>(QKVM + 3072, 4096, AO, g1, be1, X1);
  // 10) t = relu(x1 @ wf1 + bf1)   (n128, grid 8x32=256)
  gemm256n128<true, true, true><<<dim3(8, 32, 1), 512, 98304, stream>>>(
      X1, 0, 1024, W_F1_T, 0, 1024, bf1, T, 0, 1024, 1024, 1.0f);
  // 11) f = t @ wf2 + bf2 (bf16)   (n128, grid 8x32=256)
  gemm256n128<false, true, true><<<dim3(8, 32, 1), 512, 98304, stream>>>(
      T, 0, 1024, W_F2_T, 0, 1024, bf2, F, 0, 1024, 1024, 1.0f);
  // 12) out = relu(LN(x1 + f))
  add_ln_relu_k<<<8192, 256, 0, stream>>>(X1, F, g2, be2, (float*)d_out);
}